// Round 7
// baseline (1421.153 us; speedup 1.0000x reference)
//
#include <hip/hip_runtime.h>
#include <math.h>

#define NT 3072
#define DIM 512
#define NH 8
#define DKH 64
#define PKN 8
#define D2 1024
#define NL 3
#define QS 2048  // row stride of fused qkvg buffer

typedef float4 f4;
typedef unsigned short ushort_t;
typedef unsigned char uchar_t;
typedef __attribute__((ext_vector_type(8))) short s8x;
typedef __attribute__((ext_vector_type(4))) float fx4;

#define MFMA(a, b, c) __builtin_amdgcn_mfma_f32_16x16x32_bf16(a, b, c, 0, 0, 0)
#define EX2(x) __builtin_amdgcn_exp2f(x)

__device__ __forceinline__ float b2f(ushort_t u) {
  union { unsigned int x; float f; } c;
  c.x = (unsigned int)u << 16;
  return c.f;
}
__device__ __forceinline__ ushort_t f2b(float f) {
  union { float f; unsigned int x; } c;
  c.f = f;
  unsigned int r = (c.x + 0x7FFFu + ((c.x >> 16) & 1u)) >> 16;
  return (ushort_t)r;
}
__device__ __forceinline__ float wred_sum(float v) {
#pragma unroll
  for (int off = 32; off > 0; off >>= 1) v += __shfl_xor(v, off);
  return v;
}
__device__ __forceinline__ void gload16(const ushort_t* g, ushort_t* l) {
  __builtin_amdgcn_global_load_lds(
      (const __attribute__((address_space(1))) unsigned int*)(const void*)g,
      (__attribute__((address_space(3))) unsigned int*)(void*)l, 16, 0, 0);
}

// ---------------- LayerNorm -> bf16 ----------------
__global__ __launch_bounds__(256) void ln_bf16_kernel(
    const float* __restrict__ x, const float* __restrict__ s,
    const float* __restrict__ b, ushort_t* __restrict__ out) {
  int row = blockIdx.x;
  const float* xr = x + (size_t)row * DIM;
  int t = threadIdx.x;
  float v0 = xr[t], v1 = xr[t + 256];
  float sum = wred_sum(v0 + v1);
  float sq = wred_sum(v0 * v0 + v1 * v1);
  __shared__ float ss[4], s2[4];
  if ((t & 63) == 0) { ss[t >> 6] = sum; s2[t >> 6] = sq; }
  __syncthreads();
  float tot = ss[0] + ss[1] + ss[2] + ss[3];
  float tot2 = s2[0] + s2[1] + s2[2] + s2[3];
  float mean = tot * (1.0f / DIM);
  float var = tot2 * (1.0f / DIM) - mean * mean;
  float inv = rsqrtf(var + 1e-6f);
  ushort_t* orow = out + (size_t)row * DIM;
  orow[t] = f2b((v0 - mean) * inv * s[t] + b[t]);
  orow[t + 256] = f2b((v1 - mean) * inv * s[t + 256] + b[t + 256]);
}

// ---------------- per-layer weight transpose+convert (all 3 layers) ------
__device__ __forceinline__ void tconv_body(const float* __restrict__ W,
                                           ushort_t* __restrict__ Wt, int K,
                                           int Nc, int tx, int ty) {
  __shared__ float Ls[64][65];
  int t = threadIdx.x;
  int n0 = tx * 64, k0 = ty * 64;
  int rr = t >> 4, cc = (t & 15) * 4;
#pragma unroll
  for (int p = 0; p < 4; ++p) {
    f4 v = *(const f4*)&W[(size_t)(k0 + rr + p * 16) * Nc + n0 + cc];
    Ls[rr + p * 16][cc + 0] = v.x;
    Ls[rr + p * 16][cc + 1] = v.y;
    Ls[rr + p * 16][cc + 2] = v.z;
    Ls[rr + p * 16][cc + 3] = v.w;
  }
  __syncthreads();
  int nr = t >> 2, kc = (t & 3) * 16;
  ushort_t tmp[16];
#pragma unroll
  for (int e = 0; e < 16; ++e) tmp[e] = f2b(Ls[kc + e][nr]);
  ushort_t* dst = &Wt[(size_t)(n0 + nr) * K + k0 + kc];
  *(uint4*)dst = *(uint4*)&tmp[0];
  *(uint4*)(dst + 8) = *(uint4*)&tmp[8];
}

__global__ __launch_bounds__(256) void wprep_kernel(
    const float* __restrict__ Wq, const float* __restrict__ Wk,
    const float* __restrict__ Wv, const float* __restrict__ Wg,
    const float* __restrict__ Wo, const float* __restrict__ W1,
    const float* __restrict__ W2, ushort_t* __restrict__ Wt) {
  int n = blockIdx.y;
  size_t wo5 = (size_t)n * 262144;
  ushort_t* Wtl = Wt + (size_t)n * 2359296;
  int bid = blockIdx.x;
  if (bid < 320) {
    int job = bid >> 6, tile = bid & 63;
    const float* src = job == 0 ? Wq + wo5 : job == 1 ? Wk + wo5
                       : job == 2 ? Wv + wo5 : job == 3 ? Wg + wo5 : Wo + wo5;
    tconv_body(src, Wtl + (size_t)job * 262144, 512, 512, tile & 7, tile >> 3);
  } else if (bid < 448) {
    int tile = bid - 320;
    tconv_body(W1 + (size_t)n * 524288, Wtl + 1310720, 512, 1024, tile & 15,
               tile >> 4);
  } else {
    int tile = bid - 448;
    tconv_body(W2 + (size_t)n * 524288, Wtl + 1835008, 1024, 512, tile & 7,
               tile >> 3);
  }
}

// ---------------- adm int32 -> int8 ----------------
__global__ __launch_bounds__(256) void adm8_kernel(const int* __restrict__ adm,
                                                   uchar_t* __restrict__ out) {
  size_t i = ((size_t)blockIdx.x * 256 + threadIdx.x) * 4;
  int4 v = *(const int4*)&adm[i];
  unsigned int b = (unsigned)(v.x & 255) | ((unsigned)(v.y & 255) << 8) |
                   ((unsigned)(v.z & 255) << 16) | ((unsigned)(v.w & 255) << 24);
  *(unsigned int*)&out[i] = b;
}

// ---------------- V transpose per head: vbT[h][d][j] = v[j][h*64+d] ------
__global__ __launch_bounds__(256) void vt_kernel(const ushort_t* __restrict__ v,
                                                 ushort_t* __restrict__ vbT) {
  int jt = blockIdx.x, h = blockIdx.y;
  __shared__ ushort_t L[64][72];
  int t = threadIdx.x;
  int r = t >> 2, c = (t & 3) * 16;
  const ushort_t* src = v + (size_t)(jt * 64 + r) * QS + h * 64 + c;
  *(uint4*)&L[r][c] = *(const uint4*)src;
  *(uint4*)&L[r][c + 8] = *(const uint4*)(src + 8);
  __syncthreads();
  int d = t >> 2, j0 = (t & 3) * 16;
  ushort_t tmp[16];
#pragma unroll
  for (int e = 0; e < 16; ++e) tmp[e] = L[j0 + e][d];
  ushort_t* dst = vbT + (size_t)(h * 64 + d) * NT + jt * 64 + j0;
  *(uint4*)dst = *(uint4*)&tmp[0];
  *(uint4*)(dst + 8) = *(uint4*)&tmp[8];
}

// ---------------- bf16 MFMA GEMM, 64x64 tile, BK=64, dbuf + gload_lds ----
// ACT: 0 none, 1 sigmoid, 2 gelu(tanh), 3 fused-QKVG epilogue
template <int ACT, bool OBF>
__global__ __launch_bounds__(256) void gemm64(
    const ushort_t* __restrict__ A, const ushort_t* __restrict__ Bt,
    const float* __restrict__ bias, const float* __restrict__ res,
    void* __restrict__ Cp, int K, int ldc, float scale) {
  __shared__ __align__(16) ushort_t As[2][4096];
  __shared__ __align__(16) ushort_t Bs[2][4096];
  int t = threadIdx.x;
  int i0 = blockIdx.y * 64, j0 = blockIdx.x * 64;
  int w = t >> 6, l = t & 63;
  int wm = w >> 1, wn = w & 1;
  int lr = l >> 4, lc = l & 15;
  int sr = t >> 3;
  int sc8 = ((t & 7) ^ (sr & 7)) * 8;
  const ushort_t* aS = A + (size_t)(i0 + sr) * K + sc8;
  const ushort_t* bS = Bt + (size_t)(j0 + sr) * K + sc8;
  int sA0 = (wm * 32 + lc) * 64 + ((lr ^ (lc & 7)) * 8);
  int sA1 = (wm * 32 + 16 + lc) * 64 + ((lr ^ (lc & 7)) * 8);
  int sB0 = (wn * 32 + lc) * 64 + ((lr ^ (lc & 7)) * 8);
  int sB1 = (wn * 32 + 16 + lc) * 64 + ((lr ^ (lc & 7)) * 8);

  fx4 acc[2][2] = {};

#define G64_STAGE(buf, k0)                                                   \
  {                                                                          \
    gload16(aS + (k0), &As[buf][t * 8]);                                     \
    gload16(aS + (k0) + (size_t)32 * K, &As[buf][2048 + t * 8]);             \
    gload16(bS + (k0), &Bs[buf][t * 8]);                                     \
    gload16(bS + (k0) + (size_t)32 * K, &Bs[buf][2048 + t * 8]);             \
  }

  G64_STAGE(0, 0);
  __syncthreads();
  int cur = 0;
  for (int k0 = 0; k0 < K; k0 += 64) {
    if (k0 + 64 < K) G64_STAGE(cur ^ 1, k0 + 64);
    const ushort_t* Ac = As[cur];
    const ushort_t* Bc = Bs[cur];
#pragma unroll
    for (int ks = 0; ks < 2; ++ks) {
      s8x a0 = *(const s8x*)&Ac[sA0 ^ (ks << 5)];
      s8x a1 = *(const s8x*)&Ac[sA1 ^ (ks << 5)];
      s8x b0 = *(const s8x*)&Bc[sB0 ^ (ks << 5)];
      s8x b1 = *(const s8x*)&Bc[sB1 ^ (ks << 5)];
      acc[0][0] = MFMA(a0, b0, acc[0][0]);
      acc[0][1] = MFMA(a0, b1, acc[0][1]);
      acc[1][0] = MFMA(a1, b0, acc[1][0]);
      acc[1][1] = MFMA(a1, b1, acc[1][1]);
    }
    __syncthreads();
    cur ^= 1;
  }
#undef G64_STAGE

#pragma unroll
  for (int ms = 0; ms < 2; ++ms) {
#pragma unroll
    for (int ns = 0; ns < 2; ++ns) {
#pragma unroll
      for (int r = 0; r < 4; ++r) {
        int i = i0 + wm * 32 + ms * 16 + lr * 4 + r;
        int j = j0 + wn * 32 + ns * 16 + lc;
        float o = acc[ms][ns][r] * scale;
        if (ACT == 3) {
          if (blockIdx.x < 8) o *= 0.18033688011112042f;  // 0.125*log2(e)
          if (blockIdx.x >= 24) {
            o += bias[j & 511];
            o = 1.0f / (1.0f + __expf(-o));
          }
        } else {
          if (bias) o += bias[j];
          if (ACT == 1) {
            o = 1.0f / (1.0f + __expf(-o));
          } else if (ACT == 2) {
            float xx = o;
            float c2 = 1.5957691216057308f * (xx + 0.044715f * xx * xx * xx);
            o = xx / (1.0f + __expf(-c2));  // == 0.5x(1+tanh(c))
          }
          if (res) o += res[(size_t)i * ldc + j];
        }
        if (OBF)
          ((ushort_t*)Cp)[(size_t)i * ldc + j] = f2b(o);
        else
          ((float*)Cp)[(size_t)i * ldc + j] = o;
      }
    }
  }
}

// ---------------- fused attention (swapped-operand flash, 2 passes) -------
__device__ __forceinline__ float rq_sel(const unsigned int* rqt,
                                        unsigned int idx) {
  unsigned int d01 = (idx & 2) ? rqt[1] : rqt[0];
  unsigned int d23 = (idx & 2) ? rqt[3] : rqt[2];
  unsigned int dd = (idx & 4) ? d23 : d01;
  unsigned int r = (idx & 1) ? (dd & 0xffff0000u) : (dd << 16);
  return __uint_as_float(r);
}

__global__ __launch_bounds__(256) void attn_kernel(
    const ushort_t* __restrict__ xqkvg, const ushort_t* __restrict__ vbT,
    const float* __restrict__ relk, const uchar_t* __restrict__ adm8,
    float* __restrict__ att, ushort_t* __restrict__ av) {
  int f = blockIdx.y * (NT / 32) + blockIdx.x;
  int h = f & 7;          // head per XCD (T1 swizzle)
  int i0 = (f >> 3) * 32;
  int t = threadIdx.x, w = t >> 6, l = t & 63;
  int lr = l >> 4, lc = l & 15;
  int ig = w & 1, jh = w >> 1;
  int i_loc = ig * 16 + lc;
  int i = i0 + i_loc;

  __shared__ __align__(16) ushort_t Kd[2][2][4096];  // [buf][jh] 32KB
  __shared__ __align__(16) ushort_t Vd[2][2][4096];  // 32KB
  __shared__ __align__(16) ushort_t Ps[2][2048];     // 8KB
  __shared__ float MLs[2][2][16][2];

  int stgo = ig * 2048;
  int srow = ig * 32 + (l >> 3);
  int kp8 = ((l & 7) ^ ((l >> 3) & 7)) * 8;
  const ushort_t* kSrc0 =
      xqkvg + 512 + (size_t)(jh * 64 + srow) * QS + h * 64 + kp8;
  const ushort_t* vSrc0 = vbT + (size_t)(h * 64 + srow) * NT + jh * 64 + kp8;
  const uchar_t* admp0 = adm8 + (size_t)i * NT + jh * 64 + lr * 4;

#define STAGE_K(buf, tt)                                                     \
  {                                                                          \
    const ushort_t* ks_ = kSrc0 + (size_t)(tt) * 128 * QS;                   \
    gload16(ks_, Kd[buf][jh] + stgo);                                        \
    gload16(ks_ + (size_t)8 * QS, Kd[buf][jh] + stgo + 512);                 \
    gload16(ks_ + (size_t)16 * QS, Kd[buf][jh] + stgo + 1024);               \
    gload16(ks_ + (size_t)24 * QS, Kd[buf][jh] + stgo + 1536);               \
  }
#define STAGE_V(buf, tt)                                                     \
  {                                                                          \
    const ushort_t* vs_ = vSrc0 + (tt) * 128;                                \
    gload16(vs_, Vd[buf][jh] + stgo);                                        \
    gload16(vs_ + (size_t)8 * NT, Vd[buf][jh] + stgo + 512);                 \
    gload16(vs_ + (size_t)16 * NT, Vd[buf][jh] + stgo + 1024);               \
    gload16(vs_ + (size_t)24 * NT, Vd[buf][jh] + stgo + 1536);               \
  }

  STAGE_K(0, 0);  // prologue: tile 0 in flight while rq computes

  const ushort_t* qp = xqkvg + (size_t)i * QS + h * 64 + lr * 8;
  s8x qf0 = *(const s8x*)qp;
  s8x qf1 = *(const s8x*)(qp + 32);

  // rq table (in-register)
  unsigned int rqt[4];
  {
    const ushort_t* q0 = (const ushort_t*)&qf0;
    const ushort_t* q1 = (const ushort_t*)&qf1;
    float sp[8];
#pragma unroll
    for (int p = 0; p < 8; ++p) {
      const float* rp = relk + p * 64 + lr * 8;
      float s = 0.f;
#pragma unroll
      for (int e = 0; e < 8; ++e) s = fmaf(b2f(q0[e]), rp[e], s);
#pragma unroll
      for (int e = 0; e < 8; ++e) s = fmaf(b2f(q1[e]), rp[32 + e], s);
      s += __shfl_xor(s, 16);
      s += __shfl_xor(s, 32);
      sp[p] = s;
    }
#pragma unroll
    for (int j = 0; j < 4; ++j)
      rqt[j] = (unsigned int)f2b(sp[2 * j]) |
               ((unsigned int)f2b(sp[2 * j + 1]) << 16);
  }

  int sw = (lc & 7);
  int a_b0 = lc * 64 + ((lr ^ sw) << 3);
  int a_b1 = lc * 64 + (((4 + lr) ^ sw) << 3);
  int pb0 = i_loc * 64 + ((lr ^ sw) << 3);
  int pb1 = i_loc * 64 + (((4 + lr) ^ sw) << 3);
  int swz8 = sw << 3;

  float m_run = -1e30f, l_run = 0.f;
  __syncthreads();  // tile0 staged

  // ================= pass 1: running max/sum (dbuf, 1 barrier/tile) ======
  {
    int cur = 0;
    for (int tt = 0; tt < 24; ++tt) {
      if (tt < 23) STAGE_K(cur ^ 1, tt + 1);
      const ushort_t* KS = Kd[cur][jh];
      const uchar_t* admp = admp0 + tt * 128;
      fx4 sacc[4] = {};
#pragma unroll
      for (int ja = 0; ja < 4; ++ja) {
        s8x a0 = *(const s8x*)(KS + a_b0 + ja * 1024);
        s8x a1 = *(const s8x*)(KS + a_b1 + ja * 1024);
        sacc[ja] = MFMA(a0, qf0, sacc[ja]);
        sacc[ja] = MFMA(a1, qf1, sacc[ja]);
      }
      float sv[4][4];
      float tm = -1e30f;
#pragma unroll
      for (int ja = 0; ja < 4; ++ja) {
        unsigned int aw = *(const unsigned int*)(admp + ja * 16);
#pragma unroll
        for (int r = 0; r < 4; ++r) {
          float vv = sacc[ja][r] + rq_sel(rqt, (aw >> (8 * r)) & 7u);
          sv[ja][r] = vv;
          tm = fmaxf(tm, vv);
        }
      }
      float mn = fmaxf(m_run, tm);
      float sum = 0.f;
#pragma unroll
      for (int ja = 0; ja < 4; ++ja)
#pragma unroll
        for (int r = 0; r < 4; ++r) sum += EX2(sv[ja][r] - mn);
      l_run = l_run * EX2(m_run - mn) + sum;
      m_run = mn;
      __syncthreads();
      cur ^= 1;
    }
  }

  // prologue for pass 2 (overlap with m/l merge)
  STAGE_K(0, 0);
  STAGE_V(0, 0);

#pragma unroll
  for (int off = 16; off <= 32; off <<= 1) {
    float mo = __shfl_xor(m_run, off), lo = __shfl_xor(l_run, off);
    float mn = fmaxf(m_run, mo);
    l_run = l_run * EX2(m_run - mn) + lo * EX2(mo - mn);
    m_run = mn;
  }
  if (l < 16) {
    MLs[jh][ig][lc][0] = m_run;
    MLs[jh][ig][lc][1] = l_run;
  }
  __syncthreads();  // MLs + pass2 tile0 staged
  {
    float mo = MLs[jh ^ 1][ig][lc][0], lo = MLs[jh ^ 1][ig][lc][1];
    float mn = fmaxf(m_run, mo);
    l_run = l_run * EX2(m_run - mn) + lo * EX2(mo - mn);
    m_run = mn;
  }
  float lofs = m_run + __log2f(l_run);

  // ================= pass 2: P write + att out + PV (1 barrier/tile) =====
  fx4 oacc[4] = {};
  float* attb = att + ((size_t)h * NT + i0) * NT;
  ushort_t* PS = Ps[jh];
  int jh64 = jh * 64;
  {
    int cur = 0;
    for (int tt = 0; tt < 24; ++tt) {
      if (tt < 23) {
        STAGE_K(cur ^ 1, tt + 1);
        STAGE_V(cur ^ 1, tt + 1);
      }
      const ushort_t* KS = Kd[cur][jh];
      const ushort_t* VS = Vd[cur][jh];
      const uchar_t* admp = admp0 + tt * 128;
      fx4 sacc[4] = {};
#pragma unroll
      for (int ja = 0; ja < 4; ++ja) {
        s8x a0 = *(const s8x*)(KS + a_b0 + ja * 1024);
        s8x a1 = *(const s8x*)(KS + a_b1 + ja * 1024);
        sacc[ja] = MFMA(a0, qf0, sacc[ja]);
        sacc[ja] = MFMA(a1, qf1, sacc[ja]);
      }
#pragma unroll
      for (int ja = 0; ja < 4; ++ja) {
        unsigned int aw = *(const unsigned int*)(admp + ja * 16);
        float p0 = EX2(sacc[ja][0] + rq_sel(rqt, aw & 7u) - lofs);
        float p1 = EX2(sacc[ja][1] + rq_sel(rqt, (aw >> 8) & 7u) - lofs);
        float p2 = EX2(sacc[ja][2] + rq_sel(rqt, (aw >> 16) & 7u) - lofs);
        float p3 = EX2(sacc[ja][3] + rq_sel(rqt, (aw >> 24) & 7u) - lofs);
        unsigned int w01 = (unsigned int)f2b(p0) | ((unsigned int)f2b(p1) << 16);
        unsigned int w23 = (unsigned int)f2b(p2) | ((unsigned int)f2b(p3) << 16);
        int cb = ja * 16 + lr * 4;
        *(unsigned int*)&PS[i_loc * 64 + (cb ^ swz8)] = w01;
        *(unsigned int*)&PS[i_loc * 64 + ((cb + 2) ^ swz8)] = w23;
      }
      __syncthreads();
      // coalesced att copy-out (nontemporal: evict-first; drains under PV)
      {
        int uu = ig * 64 + l;
        int row = uu >> 2, cs = (uu & 3) * 16;
        int rsw = (row & 7) << 3;
        uint4 A_ = *(const uint4*)&PS[row * 64 + (cs ^ rsw)];
        uint4 B_ = *(const uint4*)&PS[row * 64 + ((cs + 8) ^ rsw)];
        const ushort_t* ap = (const ushort_t*)&A_;
        const ushort_t* bp = (const ushort_t*)&B_;
        float* op = attb + (size_t)row * NT + tt * 128 + jh64 + cs;
        fx4 o0 = {b2f(ap[0]), b2f(ap[1]), b2f(ap[2]), b2f(ap[3])};
        fx4 o1 = {b2f(ap[4]), b2f(ap[5]), b2f(ap[6]), b2f(ap[7])};
        fx4 o2 = {b2f(bp[0]), b2f(bp[1]), b2f(bp[2]), b2f(bp[3])};
        fx4 o3 = {b2f(bp[4]), b2f(bp[5]), b2f(bp[6]), b2f(bp[7])};
        __builtin_nontemporal_store(o0, (fx4*)(op + 0));
        __builtin_nontemporal_store(o1, (fx4*)(op + 4));
        __builtin_nontemporal_store(o2, (fx4*)(op + 8));
        __builtin_nontemporal_store(o3, (fx4*)(op + 12));
      }
      // PV: Ot[d][i] += Vt[d][j] * P[i][j]
#pragma unroll
      for (int ks = 0; ks < 2; ++ks) {
        s8x pf = *(const s8x*)(PS + (ks == 0 ? pb0 : pb1));
#pragma unroll
        for (int nd = 0; nd < 4; ++nd) {
          s8x vf = *(const s8x*)(VS + (ks == 0 ? a_b0 : a_b1) + nd * 1024);
          oacc[nd] = MFMA(vf, pf, oacc[nd]);
        }
      }
      __syncthreads();
      cur ^= 1;
    }
  }
#undef STAGE_K
#undef STAGE_V

  // merge O across j-halves via Ps (bf16), apply gate, write av
  ushort_t* PsF = &Ps[0][0];
  int swzO = (i_loc & 7) << 3;
  if (jh == 1) {
#pragma unroll
    for (int nd = 0; nd < 4; ++nd) {
      int d0 = nd * 16 + lr * 4;
      unsigned int lo = (unsigned int)f2b(oacc[nd][0]) |
                        ((unsigned int)f2b(oacc[nd][1]) << 16);
      unsigned int hi = (unsigned int)f2b(oacc[nd][2]) |
                        ((unsigned int)f2b(oacc[nd][3]) << 16);
      uint2 pk = {lo, hi};
      *(uint2*)&PsF[i_loc * 64 + (d0 ^ swzO)] = pk;
    }
  }
  __syncthreads();
  if (jh == 0) {
    const ushort_t* gp = xqkvg + (size_t)i * QS + 1536 + h * 64;
#pragma unroll
    for (int nd = 0; nd < 4; ++nd) {
      int d0 = nd * 16 + lr * 4;
      uint2 pk = *(const uint2*)&PsF[i_loc * 64 + (d0 ^ swzO)];
      const ushort_t* pp = (const ushort_t*)&pk;
      uint2 gk = *(const uint2*)(gp + d0);
      const ushort_t* gg = (const ushort_t*)&gk;
      ushort_t ot[4];
#pragma unroll
      for (int r = 0; r < 4; ++r)
        ot[r] = f2b((oacc[nd][r] + b2f(pp[r])) * b2f(gg[r]));
      *(uint2*)&av[(size_t)i * DIM + h * 64 + d0] = *(uint2*)ot;
    }
  }
}

extern "C" void kernel_launch(void* const* d_in, const int* in_sizes, int n_in,
                              void* d_out, int out_size, void* d_ws,
                              size_t ws_size, hipStream_t stream) {
  const float* x_in = (const float*)d_in[0];
  const int* adm = (const int*)d_in[1];
  const float* ln_att_s = (const float*)d_in[2];
  const float* ln_att_b = (const float*)d_in[3];
  const float* Wq = (const float*)d_in[4];
  const float* Wk = (const float*)d_in[5];
  const float* Wv = (const float*)d_in[6];
  const float* rel_k = (const float*)d_in[7];
  const float* Wg = (const float*)d_in[8];
  const float* bg = (const float*)d_in[9];
  const float* Wo = (const float*)d_in[10];
  const float* bo = (const float*)d_in[11];
  const float* ln_ff_s = (const float*)d_in[12];
  const float* ln_ff_b = (const float*)d_in[13];
  const float* W1 = (const float*)d_in[14];
  const float* b1 = (const float*)d_in[15];
  const float* W2 = (const float*)d_in[16];
  const float* b2 = (const float*)d_in[17];
  float* out = (float*)d_out;

  const size_t ND = (size_t)NT * DIM;
  char* ws = (char*)d_ws;
  float* x_cur = (float*)ws;                    // 6.29 MB
  float* y = (float*)(ws + 6291456);            // 6.29 MB
  ushort_t* xqkvg = (ushort_t*)(ws + 12582912); // 12.58 MB [3072][2048]
  ushort_t* avb = (ushort_t*)(ws + 25165824);   // 3.15 MB
  ushort_t* xnb = (ushort_t*)(ws + 28311552);   // 3.15 MB
  ushort_t* vbT = (ushort_t*)(ws + 31457280);   // 3.15 MB [8][64][3072]
  uchar_t* adm8 = (uchar_t*)(ws + 34603008);    // 9.44 MB
  ushort_t* Wt = (ushort_t*)(ws + 44040192);    // 14.2 MB (3 layers)
  ushort_t* h1b = xqkvg;                        // FFN hidden aliases xqkvg

  adm8_kernel<<<(NT * NT) / 1024, 256, 0, stream>>>(adm, adm8);
  wprep_kernel<<<dim3(576, 3), 256, 0, stream>>>(Wq, Wk, Wv, Wg, Wo, W1, W2,
                                                 Wt);

  dim3 gQKVG(32, NT / 64);
  dim3 gA(8, NT / 64);
  dim3 gF1(16, NT / 64);

  for (int n = 0; n < NL; ++n) {
    float* att = out + ND + (size_t)n * NH * NT * NT;
    const float* xprev = (n == 0) ? x_in : x_cur;   // residual stream input
    float* xout = (n == NL - 1) ? out : x_cur;      // final layer -> d_out
    ushort_t* Wtl = Wt + (size_t)n * 2359296;

    ln_bf16_kernel<<<NT, 256, 0, stream>>>(xprev, ln_att_s + n * DIM,
                                           ln_att_b + n * DIM, xnb);
    // fused QKVG: cols [0,512)=q(scaled), [512,1024)=k, [1024,1536)=v,
    // [1536,2048)=sigmoid(g+bg)
    gemm64<3, true><<<gQKVG, 256, 0, stream>>>(xnb, Wtl, bg + n * DIM, nullptr,
                                               xqkvg, DIM, QS, 1.0f);
    vt_kernel<<<dim3(NT / 64, NH), 256, 0, stream>>>(xqkvg + 1024, vbT);
    attn_kernel<<<dim3(NT / 32, NH), 256, 0, stream>>>(
        xqkvg, vbT, rel_k + n * PKN * DKH, adm8, att, avb);
    // y = x + (av*gate)@Wo + bo   (gate already folded into avb)
    gemm64<0, false><<<gA, 256, 0, stream>>>(avb, Wtl + 1048576, bo + n * DIM,
                                             xprev, y, DIM, DIM, 1.0f);
    ln_bf16_kernel<<<NT, 256, 0, stream>>>(y, ln_ff_s + n * DIM,
                                           ln_ff_b + n * DIM, xnb);
    gemm64<2, true><<<gF1, 256, 0, stream>>>(xnb, Wtl + 1310720, b1 + n * D2,
                                             nullptr, h1b, DIM, D2, 1.0f);
    // x_new = x_old + ff  (last layer writes straight to d_out)
    gemm64<0, false><<<gA, 256, 0, stream>>>(h1b, Wtl + 1835008, b2 + n * DIM,
                                             xprev, xout, D2, DIM, 1.0f);
  }
}

// Round 8
// 1136.118 us; speedup vs baseline: 1.2509x; 1.2509x over previous
//
#include <hip/hip_runtime.h>
#include <math.h>

#define NT 3072
#define DIM 512
#define NH 8
#define DKH 64
#define PKN 8
#define D2 1024
#define NL 3
#define QS 2048  // row stride of fused qkvg buffer

typedef float4 f4;
typedef unsigned short ushort_t;
typedef unsigned char uchar_t;
typedef __attribute__((ext_vector_type(8))) short s8x;
typedef __attribute__((ext_vector_type(4))) float fx4;

#define MFMA(a, b, c) __builtin_amdgcn_mfma_f32_16x16x32_bf16(a, b, c, 0, 0, 0)
#define EX2(x) __builtin_amdgcn_exp2f(x)

__device__ __forceinline__ float b2f(ushort_t u) {
  union { unsigned int x; float f; } c;
  c.x = (unsigned int)u << 16;
  return c.f;
}
__device__ __forceinline__ ushort_t f2b(float f) {
  union { float f; unsigned int x; } c;
  c.f = f;
  unsigned int r = (c.x + 0x7FFFu + ((c.x >> 16) & 1u)) >> 16;
  return (ushort_t)r;
}
__device__ __forceinline__ float wred_sum(float v) {
#pragma unroll
  for (int off = 32; off > 0; off >>= 1) v += __shfl_xor(v, off);
  return v;
}
__device__ __forceinline__ void gload16(const ushort_t* g, ushort_t* l) {
  __builtin_amdgcn_global_load_lds(
      (const __attribute__((address_space(1))) unsigned int*)(const void*)g,
      (__attribute__((address_space(3))) unsigned int*)(void*)l, 16, 0, 0);
}

// ---------------- LayerNorm -> bf16 ----------------
__global__ __launch_bounds__(256) void ln_bf16_kernel(
    const float* __restrict__ x, const float* __restrict__ s,
    const float* __restrict__ b, ushort_t* __restrict__ out) {
  int row = blockIdx.x;
  const float* xr = x + (size_t)row * DIM;
  int t = threadIdx.x;
  float v0 = xr[t], v1 = xr[t + 256];
  float sum = wred_sum(v0 + v1);
  float sq = wred_sum(v0 * v0 + v1 * v1);
  __shared__ float ss[4], s2[4];
  if ((t & 63) == 0) { ss[t >> 6] = sum; s2[t >> 6] = sq; }
  __syncthreads();
  float tot = ss[0] + ss[1] + ss[2] + ss[3];
  float tot2 = s2[0] + s2[1] + s2[2] + s2[3];
  float mean = tot * (1.0f / DIM);
  float var = tot2 * (1.0f / DIM) - mean * mean;
  float inv = rsqrtf(var + 1e-6f);
  ushort_t* orow = out + (size_t)row * DIM;
  orow[t] = f2b((v0 - mean) * inv * s[t] + b[t]);
  orow[t + 256] = f2b((v1 - mean) * inv * s[t + 256] + b[t + 256]);
}

// ---------------- per-layer weight transpose+convert (all 3 layers) ------
__device__ __forceinline__ void tconv_body(const float* __restrict__ W,
                                           ushort_t* __restrict__ Wt, int K,
                                           int Nc, int tx, int ty) {
  __shared__ float Ls[64][65];
  int t = threadIdx.x;
  int n0 = tx * 64, k0 = ty * 64;
  int rr = t >> 4, cc = (t & 15) * 4;
#pragma unroll
  for (int p = 0; p < 4; ++p) {
    f4 v = *(const f4*)&W[(size_t)(k0 + rr + p * 16) * Nc + n0 + cc];
    Ls[rr + p * 16][cc + 0] = v.x;
    Ls[rr + p * 16][cc + 1] = v.y;
    Ls[rr + p * 16][cc + 2] = v.z;
    Ls[rr + p * 16][cc + 3] = v.w;
  }
  __syncthreads();
  int nr = t >> 2, kc = (t & 3) * 16;
  ushort_t tmp[16];
#pragma unroll
  for (int e = 0; e < 16; ++e) tmp[e] = f2b(Ls[kc + e][nr]);
  ushort_t* dst = &Wt[(size_t)(n0 + nr) * K + k0 + kc];
  *(uint4*)dst = *(uint4*)&tmp[0];
  *(uint4*)(dst + 8) = *(uint4*)&tmp[8];
}

__global__ __launch_bounds__(256) void wprep_kernel(
    const float* __restrict__ Wq, const float* __restrict__ Wk,
    const float* __restrict__ Wv, const float* __restrict__ Wg,
    const float* __restrict__ Wo, const float* __restrict__ W1,
    const float* __restrict__ W2, ushort_t* __restrict__ Wt) {
  int n = blockIdx.y;
  size_t wo5 = (size_t)n * 262144;
  ushort_t* Wtl = Wt + (size_t)n * 2359296;
  int bid = blockIdx.x;
  if (bid < 320) {
    int job = bid >> 6, tile = bid & 63;
    const float* src = job == 0 ? Wq + wo5 : job == 1 ? Wk + wo5
                       : job == 2 ? Wv + wo5 : job == 3 ? Wg + wo5 : Wo + wo5;
    tconv_body(src, Wtl + (size_t)job * 262144, 512, 512, tile & 7, tile >> 3);
  } else if (bid < 448) {
    int tile = bid - 320;
    tconv_body(W1 + (size_t)n * 524288, Wtl + 1310720, 512, 1024, tile & 15,
               tile >> 4);
  } else {
    int tile = bid - 448;
    tconv_body(W2 + (size_t)n * 524288, Wtl + 1835008, 1024, 512, tile & 7,
               tile >> 3);
  }
}

// ---------------- adm int32 -> int8 ----------------
__global__ __launch_bounds__(256) void adm8_kernel(const int* __restrict__ adm,
                                                   uchar_t* __restrict__ out) {
  size_t i = ((size_t)blockIdx.x * 256 + threadIdx.x) * 4;
  int4 v = *(const int4*)&adm[i];
  unsigned int b = (unsigned)(v.x & 255) | ((unsigned)(v.y & 255) << 8) |
                   ((unsigned)(v.z & 255) << 16) | ((unsigned)(v.w & 255) << 24);
  *(unsigned int*)&out[i] = b;
}

// ---------------- V transpose per head: vbT[h][d][j] = v[j][h*64+d] ------
__global__ __launch_bounds__(256) void vt_kernel(const ushort_t* __restrict__ v,
                                                 ushort_t* __restrict__ vbT) {
  int jt = blockIdx.x, h = blockIdx.y;
  __shared__ ushort_t L[64][72];
  int t = threadIdx.x;
  int r = t >> 2, c = (t & 3) * 16;
  const ushort_t* src = v + (size_t)(jt * 64 + r) * QS + h * 64 + c;
  *(uint4*)&L[r][c] = *(const uint4*)src;
  *(uint4*)&L[r][c + 8] = *(const uint4*)(src + 8);
  __syncthreads();
  int d = t >> 2, j0 = (t & 3) * 16;
  ushort_t tmp[16];
#pragma unroll
  for (int e = 0; e < 16; ++e) tmp[e] = L[j0 + e][d];
  ushort_t* dst = vbT + (size_t)(h * 64 + d) * NT + jt * 64 + j0;
  *(uint4*)dst = *(uint4*)&tmp[0];
  *(uint4*)(dst + 8) = *(uint4*)&tmp[8];
}

// ---------------- bf16 MFMA GEMM, 64x64 tile, BK=64, dbuf + gload_lds ----
// ACT: 0 none, 1 sigmoid, 2 gelu(tanh)
template <int ACT, bool OBF>
__global__ __launch_bounds__(256) void gemm64(
    const ushort_t* __restrict__ A, const ushort_t* __restrict__ Bt,
    const float* __restrict__ bias, const float* __restrict__ res,
    void* __restrict__ Cp, int K, int ldc, float scale) {
  __shared__ __align__(16) ushort_t As[2][4096];
  __shared__ __align__(16) ushort_t Bs[2][4096];
  int t = threadIdx.x;
  int i0 = blockIdx.y * 64, j0 = blockIdx.x * 64;
  int w = t >> 6, l = t & 63;
  int wm = w >> 1, wn = w & 1;
  int lr = l >> 4, lc = l & 15;
  int sr = t >> 3;
  int sc8 = ((t & 7) ^ (sr & 7)) * 8;
  const ushort_t* aS = A + (size_t)(i0 + sr) * K + sc8;
  const ushort_t* bS = Bt + (size_t)(j0 + sr) * K + sc8;
  int sA0 = (wm * 32 + lc) * 64 + ((lr ^ (lc & 7)) * 8);
  int sA1 = (wm * 32 + 16 + lc) * 64 + ((lr ^ (lc & 7)) * 8);
  int sB0 = (wn * 32 + lc) * 64 + ((lr ^ (lc & 7)) * 8);
  int sB1 = (wn * 32 + 16 + lc) * 64 + ((lr ^ (lc & 7)) * 8);

  fx4 acc[2][2] = {};

#define G64_STAGE(buf, k0)                                                   \
  {                                                                          \
    gload16(aS + (k0), &As[buf][t * 8]);                                     \
    gload16(aS + (k0) + (size_t)32 * K, &As[buf][2048 + t * 8]);             \
    gload16(bS + (k0), &Bs[buf][t * 8]);                                     \
    gload16(bS + (k0) + (size_t)32 * K, &Bs[buf][2048 + t * 8]);             \
  }

  G64_STAGE(0, 0);
  __syncthreads();
  int cur = 0;
  for (int k0 = 0; k0 < K; k0 += 64) {
    if (k0 + 64 < K) G64_STAGE(cur ^ 1, k0 + 64);
    const ushort_t* Ac = As[cur];
    const ushort_t* Bc = Bs[cur];
#pragma unroll
    for (int ks = 0; ks < 2; ++ks) {
      s8x a0 = *(const s8x*)&Ac[sA0 ^ (ks << 5)];
      s8x a1 = *(const s8x*)&Ac[sA1 ^ (ks << 5)];
      s8x b0 = *(const s8x*)&Bc[sB0 ^ (ks << 5)];
      s8x b1 = *(const s8x*)&Bc[sB1 ^ (ks << 5)];
      acc[0][0] = MFMA(a0, b0, acc[0][0]);
      acc[0][1] = MFMA(a0, b1, acc[0][1]);
      acc[1][0] = MFMA(a1, b0, acc[1][0]);
      acc[1][1] = MFMA(a1, b1, acc[1][1]);
    }
    __syncthreads();
    cur ^= 1;
  }
#undef G64_STAGE

#pragma unroll
  for (int ms = 0; ms < 2; ++ms) {
#pragma unroll
    for (int ns = 0; ns < 2; ++ns) {
#pragma unroll
      for (int r = 0; r < 4; ++r) {
        int i = i0 + wm * 32 + ms * 16 + lr * 4 + r;
        int j = j0 + wn * 32 + ns * 16 + lc;
        float o = acc[ms][ns][r] * scale;
        if (bias) o += bias[j];
        if (ACT == 1) {
          o = 1.0f / (1.0f + __expf(-o));
        } else if (ACT == 2) {
          float xx = o;
          float c2 = 1.5957691216057308f * (xx + 0.044715f * xx * xx * xx);
          o = xx / (1.0f + __expf(-c2));  // == 0.5x(1+tanh(c))
        }
        if (res) o += res[(size_t)i * ldc + j];
        if (OBF)
          ((ushort_t*)Cp)[(size_t)i * ldc + j] = f2b(o);
        else
          ((float*)Cp)[(size_t)i * ldc + j] = o;
      }
    }
  }
}

// ---------------- bf16 MFMA GEMM, 128x128 tile, BK=32 (m97 structure) ----
// Used for the fused QKVG projection only (N=2048 -> 384 blocks).
// ACT==3 epilogue: j<512 -> q-scale; j>=1536 -> sigmoid(g + bg).
template <int ACT, bool OBF>
__global__ __launch_bounds__(256) void gemm128(
    const ushort_t* __restrict__ A, const ushort_t* __restrict__ Bt,
    const float* __restrict__ bias, const float* __restrict__ res,
    void* __restrict__ Cp, int K, int ldc, float scale) {
  __shared__ __align__(16) ushort_t As[4096];  // [128 rows][32 k]
  __shared__ __align__(16) ushort_t Bs[4096];
  int t = threadIdx.x;
  int i0 = blockIdx.y * 128, j0 = blockIdx.x * 128;
  int w = t >> 6, l = t & 63;
  int wm = w >> 1, wn = w & 1;
  int lr = l >> 4, lc = l & 15;
  // staging: thread t -> row sr (and sr+64), chunk t&3, pre-swizzled source
  int sr = t >> 2;
  int sc8 = ((t & 3) ^ ((sr >> 1) & 3)) * 8;
  const ushort_t* aS = A + (size_t)(i0 + sr) * K + sc8;
  const ushort_t* bS = Bt + (size_t)(j0 + sr) * K + sc8;
  // frag offsets: row*32 + ((lr ^ ((row>>1)&3))*8)  -> 2-way aliasing max
  int fa[4], fb[4];
#pragma unroll
  for (int f = 0; f < 4; ++f) {
    int ra = wm * 64 + f * 16 + lc;
    fa[f] = ra * 32 + ((lr ^ ((ra >> 1) & 3)) * 8);
    int rb = wn * 64 + f * 16 + lc;
    fb[f] = rb * 32 + ((lr ^ ((rb >> 1) & 3)) * 8);
  }
  fx4 acc[4][4] = {};
  for (int k0 = 0; k0 < K; k0 += 32) {
    gload16(aS + k0, &As[t * 8]);
    gload16(aS + k0 + (size_t)64 * K, &As[2048 + t * 8]);
    gload16(bS + k0, &Bs[t * 8]);
    gload16(bS + k0 + (size_t)64 * K, &Bs[2048 + t * 8]);
    __syncthreads();
    s8x af[4], bf[4];
#pragma unroll
    for (int f = 0; f < 4; ++f) {
      af[f] = *(const s8x*)&As[fa[f]];
      bf[f] = *(const s8x*)&Bs[fb[f]];
    }
#pragma unroll
    for (int ms = 0; ms < 4; ++ms)
#pragma unroll
      for (int ns = 0; ns < 4; ++ns)
        acc[ms][ns] = MFMA(af[ms], bf[ns], acc[ms][ns]);
    __syncthreads();
  }
#pragma unroll
  for (int ms = 0; ms < 4; ++ms) {
#pragma unroll
    for (int ns = 0; ns < 4; ++ns) {
#pragma unroll
      for (int r = 0; r < 4; ++r) {
        int i = i0 + wm * 64 + ms * 16 + lr * 4 + r;
        int j = j0 + wn * 64 + ns * 16 + lc;
        float o = acc[ms][ns][r] * scale;
        if (ACT == 3) {
          if (blockIdx.x < 4) o *= 0.18033688011112042f;  // 0.125*log2(e)
          if (blockIdx.x >= 12) {
            o += bias[j & 511];
            o = 1.0f / (1.0f + __expf(-o));
          }
        } else {
          if (bias) o += bias[j];
          if (res) o += res[(size_t)i * ldc + j];
        }
        if (OBF)
          ((ushort_t*)Cp)[(size_t)i * ldc + j] = f2b(o);
        else
          ((float*)Cp)[(size_t)i * ldc + j] = o;
      }
    }
  }
}

// ---------------- fused attention (swapped-operand flash, 2 passes) -------
__device__ __forceinline__ float rq_sel(const unsigned int* rqt,
                                        unsigned int idx) {
  unsigned int d01 = (idx & 2) ? rqt[1] : rqt[0];
  unsigned int d23 = (idx & 2) ? rqt[3] : rqt[2];
  unsigned int dd = (idx & 4) ? d23 : d01;
  unsigned int r = (idx & 1) ? (dd & 0xffff0000u) : (dd << 16);
  return __uint_as_float(r);
}

__global__ __launch_bounds__(256) void attn_kernel(
    const ushort_t* __restrict__ xqkvg, const ushort_t* __restrict__ vbT,
    const float* __restrict__ relk, const uchar_t* __restrict__ adm8,
    float* __restrict__ att, ushort_t* __restrict__ av) {
  int f = blockIdx.y * (NT / 32) + blockIdx.x;
  int h = f & 7;          // head per XCD (T1 swizzle)
  int i0 = (f >> 3) * 32;
  int t = threadIdx.x, w = t >> 6, l = t & 63;
  int lr = l >> 4, lc = l & 15;
  int ig = w & 1, jh = w >> 1;
  int i_loc = ig * 16 + lc;
  int i = i0 + i_loc;

  __shared__ __align__(16) ushort_t Kd[2][2][4096];  // [buf][jh] 32KB
  __shared__ __align__(16) ushort_t Vd[2][2][4096];  // 32KB
  __shared__ __align__(16) ushort_t Ps[2][2048];     // 8KB
  __shared__ float MLs[2][2][16][2];

  int stgo = ig * 2048;
  int srow = ig * 32 + (l >> 3);
  int kp8 = ((l & 7) ^ ((l >> 3) & 7)) * 8;
  const ushort_t* kSrc0 =
      xqkvg + 512 + (size_t)(jh * 64 + srow) * QS + h * 64 + kp8;
  const ushort_t* vSrc0 = vbT + (size_t)(h * 64 + srow) * NT + jh * 64 + kp8;
  const uchar_t* admp0 = adm8 + (size_t)i * NT + jh * 64 + lr * 4;

#define STAGE_K(buf, tt)                                                     \
  {                                                                          \
    const ushort_t* ks_ = kSrc0 + (size_t)(tt) * 128 * QS;                   \
    gload16(ks_, Kd[buf][jh] + stgo);                                        \
    gload16(ks_ + (size_t)8 * QS, Kd[buf][jh] + stgo + 512);                 \
    gload16(ks_ + (size_t)16 * QS, Kd[buf][jh] + stgo + 1024);               \
    gload16(ks_ + (size_t)24 * QS, Kd[buf][jh] + stgo + 1536);               \
  }
#define STAGE_V(buf, tt)                                                     \
  {                                                                          \
    const ushort_t* vs_ = vSrc0 + (tt) * 128;                                \
    gload16(vs_, Vd[buf][jh] + stgo);                                        \
    gload16(vs_ + (size_t)8 * NT, Vd[buf][jh] + stgo + 512);                 \
    gload16(vs_ + (size_t)16 * NT, Vd[buf][jh] + stgo + 1024);               \
    gload16(vs_ + (size_t)24 * NT, Vd[buf][jh] + stgo + 1536);               \
  }

  STAGE_K(0, 0);  // prologue: tile 0 in flight while rq computes

  const ushort_t* qp = xqkvg + (size_t)i * QS + h * 64 + lr * 8;
  s8x qf0 = *(const s8x*)qp;
  s8x qf1 = *(const s8x*)(qp + 32);

  // rq table (in-register)
  unsigned int rqt[4];
  {
    const ushort_t* q0 = (const ushort_t*)&qf0;
    const ushort_t* q1 = (const ushort_t*)&qf1;
    float sp[8];
#pragma unroll
    for (int p = 0; p < 8; ++p) {
      const float* rp = relk + p * 64 + lr * 8;
      float s = 0.f;
#pragma unroll
      for (int e = 0; e < 8; ++e) s = fmaf(b2f(q0[e]), rp[e], s);
#pragma unroll
      for (int e = 0; e < 8; ++e) s = fmaf(b2f(q1[e]), rp[32 + e], s);
      s += __shfl_xor(s, 16);
      s += __shfl_xor(s, 32);
      sp[p] = s;
    }
#pragma unroll
    for (int j = 0; j < 4; ++j)
      rqt[j] = (unsigned int)f2b(sp[2 * j]) |
               ((unsigned int)f2b(sp[2 * j + 1]) << 16);
  }

  int sw = (lc & 7);
  int a_b0 = lc * 64 + ((lr ^ sw) << 3);
  int a_b1 = lc * 64 + (((4 + lr) ^ sw) << 3);
  int pb0 = i_loc * 64 + ((lr ^ sw) << 3);
  int pb1 = i_loc * 64 + (((4 + lr) ^ sw) << 3);
  int swz8 = sw << 3;

  float m_run = -1e30f, l_run = 0.f;
  __syncthreads();  // tile0 staged

  // ================= pass 1: running max/sum (dbuf, 1 barrier/tile) ======
  {
    int cur = 0;
    for (int tt = 0; tt < 24; ++tt) {
      if (tt < 23) STAGE_K(cur ^ 1, tt + 1);
      const ushort_t* KS = Kd[cur][jh];
      const uchar_t* admp = admp0 + tt * 128;
      fx4 sacc[4] = {};
#pragma unroll
      for (int ja = 0; ja < 4; ++ja) {
        s8x a0 = *(const s8x*)(KS + a_b0 + ja * 1024);
        s8x a1 = *(const s8x*)(KS + a_b1 + ja * 1024);
        sacc[ja] = MFMA(a0, qf0, sacc[ja]);
        sacc[ja] = MFMA(a1, qf1, sacc[ja]);
      }
      float sv[4][4];
      float tm = -1e30f;
#pragma unroll
      for (int ja = 0; ja < 4; ++ja) {
        unsigned int aw = *(const unsigned int*)(admp + ja * 16);
#pragma unroll
        for (int r = 0; r < 4; ++r) {
          float vv = sacc[ja][r] + rq_sel(rqt, (aw >> (8 * r)) & 7u);
          sv[ja][r] = vv;
          tm = fmaxf(tm, vv);
        }
      }
      float mn = fmaxf(m_run, tm);
      float sum = 0.f;
#pragma unroll
      for (int ja = 0; ja < 4; ++ja)
#pragma unroll
        for (int r = 0; r < 4; ++r) sum += EX2(sv[ja][r] - mn);
      l_run = l_run * EX2(m_run - mn) + sum;
      m_run = mn;
      __syncthreads();
      cur ^= 1;
    }
  }

  // prologue for pass 2 (overlap with m/l merge)
  STAGE_K(0, 0);
  STAGE_V(0, 0);

#pragma unroll
  for (int off = 16; off <= 32; off <<= 1) {
    float mo = __shfl_xor(m_run, off), lo = __shfl_xor(l_run, off);
    float mn = fmaxf(m_run, mo);
    l_run = l_run * EX2(m_run - mn) + lo * EX2(mo - mn);
    m_run = mn;
  }
  if (l < 16) {
    MLs[jh][ig][lc][0] = m_run;
    MLs[jh][ig][lc][1] = l_run;
  }
  __syncthreads();  // MLs + pass2 tile0 staged
  {
    float mo = MLs[jh ^ 1][ig][lc][0], lo = MLs[jh ^ 1][ig][lc][1];
    float mn = fmaxf(m_run, mo);
    l_run = l_run * EX2(m_run - mn) + lo * EX2(mo - mn);
    m_run = mn;
  }
  float lofs = m_run + __log2f(l_run);

  // ================= pass 2: P write + att out + PV (1 barrier/tile) =====
  fx4 oacc[4] = {};
  float* attb = att + ((size_t)h * NT + i0) * NT;
  ushort_t* PS = Ps[jh];
  int jh64 = jh * 64;
  {
    int cur = 0;
    for (int tt = 0; tt < 24; ++tt) {
      if (tt < 23) {
        STAGE_K(cur ^ 1, tt + 1);
        STAGE_V(cur ^ 1, tt + 1);
      }
      const ushort_t* KS = Kd[cur][jh];
      const ushort_t* VS = Vd[cur][jh];
      const uchar_t* admp = admp0 + tt * 128;
      fx4 sacc[4] = {};
#pragma unroll
      for (int ja = 0; ja < 4; ++ja) {
        s8x a0 = *(const s8x*)(KS + a_b0 + ja * 1024);
        s8x a1 = *(const s8x*)(KS + a_b1 + ja * 1024);
        sacc[ja] = MFMA(a0, qf0, sacc[ja]);
        sacc[ja] = MFMA(a1, qf1, sacc[ja]);
      }
#pragma unroll
      for (int ja = 0; ja < 4; ++ja) {
        unsigned int aw = *(const unsigned int*)(admp + ja * 16);
        float p0 = EX2(sacc[ja][0] + rq_sel(rqt, aw & 7u) - lofs);
        float p1 = EX2(sacc[ja][1] + rq_sel(rqt, (aw >> 8) & 7u) - lofs);
        float p2 = EX2(sacc[ja][2] + rq_sel(rqt, (aw >> 16) & 7u) - lofs);
        float p3 = EX2(sacc[ja][3] + rq_sel(rqt, (aw >> 24) & 7u) - lofs);
        unsigned int w01 = (unsigned int)f2b(p0) | ((unsigned int)f2b(p1) << 16);
        unsigned int w23 = (unsigned int)f2b(p2) | ((unsigned int)f2b(p3) << 16);
        int cb = ja * 16 + lr * 4;
        *(unsigned int*)&PS[i_loc * 64 + (cb ^ swz8)] = w01;
        *(unsigned int*)&PS[i_loc * 64 + ((cb + 2) ^ swz8)] = w23;
      }
      // att copy-out: SAME-WAVE rows only (no barrier needed); drains under PV
      {
        int uu = ig * 64 + l;
        int row = uu >> 2, cs = (uu & 3) * 16;
        int rsw = (row & 7) << 3;
        uint4 A_ = *(const uint4*)&PS[row * 64 + (cs ^ rsw)];
        uint4 B_ = *(const uint4*)&PS[row * 64 + ((cs + 8) ^ rsw)];
        const ushort_t* ap = (const ushort_t*)&A_;
        const ushort_t* bp = (const ushort_t*)&B_;
        float* op = attb + (size_t)row * NT + tt * 128 + jh64 + cs;
        f4 o0 = {b2f(ap[0]), b2f(ap[1]), b2f(ap[2]), b2f(ap[3])};
        f4 o1 = {b2f(ap[4]), b2f(ap[5]), b2f(ap[6]), b2f(ap[7])};
        f4 o2 = {b2f(bp[0]), b2f(bp[1]), b2f(bp[2]), b2f(bp[3])};
        f4 o3 = {b2f(bp[4]), b2f(bp[5]), b2f(bp[6]), b2f(bp[7])};
        *(f4*)(op + 0) = o0;
        *(f4*)(op + 4) = o1;
        *(f4*)(op + 8) = o2;
        *(f4*)(op + 12) = o3;
      }
      // PV: Ot[d][i] += Vt[d][j] * P[i][j]
#pragma unroll
      for (int ks = 0; ks < 2; ++ks) {
        s8x pf = *(const s8x*)(PS + (ks == 0 ? pb0 : pb1));
#pragma unroll
        for (int nd = 0; nd < 4; ++nd) {
          s8x vf = *(const s8x*)(VS + (ks == 0 ? a_b0 : a_b1) + nd * 1024);
          oacc[nd] = MFMA(vf, pf, oacc[nd]);
        }
      }
      __syncthreads();
      cur ^= 1;
    }
  }
#undef STAGE_K
#undef STAGE_V

  // merge O across j-halves via Ps (bf16), apply gate, write av
  ushort_t* PsF = &Ps[0][0];
  int swzO = (i_loc & 7) << 3;
  if (jh == 1) {
#pragma unroll
    for (int nd = 0; nd < 4; ++nd) {
      int d0 = nd * 16 + lr * 4;
      unsigned int lo = (unsigned int)f2b(oacc[nd][0]) |
                        ((unsigned int)f2b(oacc[nd][1]) << 16);
      unsigned int hi = (unsigned int)f2b(oacc[nd][2]) |
                        ((unsigned int)f2b(oacc[nd][3]) << 16);
      uint2 pk = {lo, hi};
      *(uint2*)&PsF[i_loc * 64 + (d0 ^ swzO)] = pk;
    }
  }
  __syncthreads();
  if (jh == 0) {
    const ushort_t* gp = xqkvg + (size_t)i * QS + 1536 + h * 64;
#pragma unroll
    for (int nd = 0; nd < 4; ++nd) {
      int d0 = nd * 16 + lr * 4;
      uint2 pk = *(const uint2*)&PsF[i_loc * 64 + (d0 ^ swzO)];
      const ushort_t* pp = (const ushort_t*)&pk;
      uint2 gk = *(const uint2*)(gp + d0);
      const ushort_t* gg = (const ushort_t*)&gk;
      ushort_t ot[4];
#pragma unroll
      for (int r = 0; r < 4; ++r)
        ot[r] = f2b((oacc[nd][r] + b2f(pp[r])) * b2f(gg[r]));
      *(uint2*)&av[(size_t)i * DIM + h * 64 + d0] = *(uint2*)ot;
    }
  }
}

extern "C" void kernel_launch(void* const* d_in, const int* in_sizes, int n_in,
                              void* d_out, int out_size, void* d_ws,
                              size_t ws_size, hipStream_t stream) {
  const float* x_in = (const float*)d_in[0];
  const int* adm = (const int*)d_in[1];
  const float* ln_att_s = (const float*)d_in[2];
  const float* ln_att_b = (const float*)d_in[3];
  const float* Wq = (const float*)d_in[4];
  const float* Wk = (const float*)d_in[5];
  const float* Wv = (const float*)d_in[6];
  const float* rel_k = (const float*)d_in[7];
  const float* Wg = (const float*)d_in[8];
  const float* bg = (const float*)d_in[9];
  const float* Wo = (const float*)d_in[10];
  const float* bo = (const float*)d_in[11];
  const float* ln_ff_s = (const float*)d_in[12];
  const float* ln_ff_b = (const float*)d_in[13];
  const float* W1 = (const float*)d_in[14];
  const float* b1 = (const float*)d_in[15];
  const float* W2 = (const float*)d_in[16];
  const float* b2 = (const float*)d_in[17];
  float* out = (float*)d_out;

  const size_t ND = (size_t)NT * DIM;
  char* ws = (char*)d_ws;
  float* x_cur = (float*)ws;                    // 6.29 MB
  float* y = (float*)(ws + 6291456);            // 6.29 MB
  ushort_t* xqkvg = (ushort_t*)(ws + 12582912); // 12.58 MB [3072][2048]
  ushort_t* avb = (ushort_t*)(ws + 25165824);   // 3.15 MB
  ushort_t* xnb = (ushort_t*)(ws + 28311552);   // 3.15 MB
  ushort_t* vbT = (ushort_t*)(ws + 31457280);   // 3.15 MB [8][64][3072]
  uchar_t* adm8 = (uchar_t*)(ws + 34603008);    // 9.44 MB
  ushort_t* Wt = (ushort_t*)(ws + 44040192);    // 14.2 MB (3 layers)
  ushort_t* h1b = xqkvg;                        // FFN hidden aliases xqkvg

  adm8_kernel<<<(NT * NT) / 1024, 256, 0, stream>>>(adm, adm8);
  wprep_kernel<<<dim3(576, 3), 256, 0, stream>>>(Wq, Wk, Wv, Wg, Wo, W1, W2,
                                                 Wt);

  dim3 gQKVG(16, NT / 128);  // 128x128 tiles, 384 blocks
  dim3 gA(8, NT / 64);
  dim3 gF1(16, NT / 64);

  for (int n = 0; n < NL; ++n) {
    float* att = out + ND + (size_t)n * NH * NT * NT;
    const float* xprev = (n == 0) ? x_in : x_cur;   // residual stream input
    float* xout = (n == NL - 1) ? out : x_cur;      // final layer -> d_out
    ushort_t* Wtl = Wt + (size_t)n * 2359296;

    ln_bf16_kernel<<<NT, 256, 0, stream>>>(xprev, ln_att_s + n * DIM,
                                           ln_att_b + n * DIM, xnb);
    // fused QKVG: cols [0,512)=q(scaled), [512,1024)=k, [1024,1536)=v,
    // [1536,2048)=sigmoid(g+bg)
    gemm128<3, true><<<gQKVG, 256, 0, stream>>>(xnb, Wtl, bg + n * DIM,
                                                nullptr, xqkvg, DIM, QS, 1.0f);
    vt_kernel<<<dim3(NT / 64, NH), 256, 0, stream>>>(xqkvg + 1024, vbT);
    attn_kernel<<<dim3(NT / 32, NH), 256, 0, stream>>>(
        xqkvg, vbT, rel_k + n * PKN * DKH, adm8, att, avb);
    // y = x + (av*gate)@Wo + bo   (gate already folded into avb)
    gemm64<0, false><<<gA, 256, 0, stream>>>(avb, Wtl + 1048576, bo + n * DIM,
                                             xprev, y, DIM, DIM, 1.0f);
    ln_bf16_kernel<<<NT, 256, 0, stream>>>(y, ln_ff_s + n * DIM,
                                           ln_ff_b + n * DIM, xnb);
    gemm64<2, true><<<gF1, 256, 0, stream>>>(xnb, Wtl + 1310720, b1 + n * D2,
                                             nullptr, h1b, DIM, D2, 1.0f);
    // x_new = x_old + ff  (last layer writes straight to d_out)
    gemm64<0, false><<<gA, 256, 0, stream>>>(h1b, Wtl + 1835008, b2 + n * DIM,
                                             xprev, xout, D2, DIM, 1.0f);
  }
}

// Round 9
// 1010.948 us; speedup vs baseline: 1.4058x; 1.1238x over previous
//
#include <hip/hip_runtime.h>
#include <math.h>

#define NT 3072
#define DIM 512
#define NH 8
#define DKH 64
#define PKN 8
#define D2 1024
#define NL 3
#define QS 2048  // row stride of fused qkvg buffer

typedef float4 f4;
typedef unsigned short ushort_t;
typedef unsigned char uchar_t;
typedef __attribute__((ext_vector_type(8))) short s8x;
typedef __attribute__((ext_vector_type(4))) float fx4;

#define MFMA(a, b, c) __builtin_amdgcn_mfma_f32_16x16x32_bf16(a, b, c, 0, 0, 0)
#define EX2(x) __builtin_amdgcn_exp2f(x)

__device__ __forceinline__ float b2f(ushort_t u) {
  union { unsigned int x; float f; } c;
  c.x = (unsigned int)u << 16;
  return c.f;
}
__device__ __forceinline__ ushort_t f2b(float f) {
  union { float f; unsigned int x; } c;
  c.f = f;
  unsigned int r = (c.x + 0x7FFFu + ((c.x >> 16) & 1u)) >> 16;
  return (ushort_t)r;
}
__device__ __forceinline__ float wred_sum(float v) {
#pragma unroll
  for (int off = 32; off > 0; off >>= 1) v += __shfl_xor(v, off);
  return v;
}
__device__ __forceinline__ void gload16(const ushort_t* g, ushort_t* l) {
  __builtin_amdgcn_global_load_lds(
      (const __attribute__((address_space(1))) unsigned int*)(const void*)g,
      (__attribute__((address_space(3))) unsigned int*)(void*)l, 16, 0, 0);
}

// ---------------- LayerNorm -> bf16 ----------------
__global__ __launch_bounds__(256) void ln_bf16_kernel(
    const float* __restrict__ x, const float* __restrict__ s,
    const float* __restrict__ b, ushort_t* __restrict__ out) {
  int row = blockIdx.x;
  const float* xr = x + (size_t)row * DIM;
  int t = threadIdx.x;
  float v0 = xr[t], v1 = xr[t + 256];
  float sum = wred_sum(v0 + v1);
  float sq = wred_sum(v0 * v0 + v1 * v1);
  __shared__ float ss[4], s2[4];
  if ((t & 63) == 0) { ss[t >> 6] = sum; s2[t >> 6] = sq; }
  __syncthreads();
  float tot = ss[0] + ss[1] + ss[2] + ss[3];
  float tot2 = s2[0] + s2[1] + s2[2] + s2[3];
  float mean = tot * (1.0f / DIM);
  float var = tot2 * (1.0f / DIM) - mean * mean;
  float inv = rsqrtf(var + 1e-6f);
  ushort_t* orow = out + (size_t)row * DIM;
  orow[t] = f2b((v0 - mean) * inv * s[t] + b[t]);
  orow[t + 256] = f2b((v1 - mean) * inv * s[t + 256] + b[t + 256]);
}

// ---------------- per-layer weight transpose+convert (all 3 layers) ------
__device__ __forceinline__ void tconv_body(const float* __restrict__ W,
                                           ushort_t* __restrict__ Wt, int K,
                                           int Nc, int tx, int ty) {
  __shared__ float Ls[64][65];
  int t = threadIdx.x;
  int n0 = tx * 64, k0 = ty * 64;
  int rr = t >> 4, cc = (t & 15) * 4;
#pragma unroll
  for (int p = 0; p < 4; ++p) {
    f4 v = *(const f4*)&W[(size_t)(k0 + rr + p * 16) * Nc + n0 + cc];
    Ls[rr + p * 16][cc + 0] = v.x;
    Ls[rr + p * 16][cc + 1] = v.y;
    Ls[rr + p * 16][cc + 2] = v.z;
    Ls[rr + p * 16][cc + 3] = v.w;
  }
  __syncthreads();
  int nr = t >> 2, kc = (t & 3) * 16;
  ushort_t tmp[16];
#pragma unroll
  for (int e = 0; e < 16; ++e) tmp[e] = f2b(Ls[kc + e][nr]);
  ushort_t* dst = &Wt[(size_t)(n0 + nr) * K + k0 + kc];
  *(uint4*)dst = *(uint4*)&tmp[0];
  *(uint4*)(dst + 8) = *(uint4*)&tmp[8];
}

__global__ __launch_bounds__(256) void wprep_kernel(
    const float* __restrict__ Wq, const float* __restrict__ Wk,
    const float* __restrict__ Wv, const float* __restrict__ Wg,
    const float* __restrict__ Wo, const float* __restrict__ W1,
    const float* __restrict__ W2, ushort_t* __restrict__ Wt) {
  int n = blockIdx.y;
  size_t wo5 = (size_t)n * 262144;
  ushort_t* Wtl = Wt + (size_t)n * 2359296;
  int bid = blockIdx.x;
  if (bid < 320) {
    int job = bid >> 6, tile = bid & 63;
    const float* src = job == 0 ? Wq + wo5 : job == 1 ? Wk + wo5
                       : job == 2 ? Wv + wo5 : job == 3 ? Wg + wo5 : Wo + wo5;
    tconv_body(src, Wtl + (size_t)job * 262144, 512, 512, tile & 7, tile >> 3);
  } else if (bid < 448) {
    int tile = bid - 320;
    tconv_body(W1 + (size_t)n * 524288, Wtl + 1310720, 512, 1024, tile & 15,
               tile >> 4);
  } else {
    int tile = bid - 448;
    tconv_body(W2 + (size_t)n * 524288, Wtl + 1835008, 1024, 512, tile & 7,
               tile >> 3);
  }
}

// ---------------- adm int32 -> int8 ----------------
__global__ __launch_bounds__(256) void adm8_kernel(const int* __restrict__ adm,
                                                   uchar_t* __restrict__ out) {
  size_t i = ((size_t)blockIdx.x * 256 + threadIdx.x) * 4;
  int4 v = *(const int4*)&adm[i];
  unsigned int b = (unsigned)(v.x & 255) | ((unsigned)(v.y & 255) << 8) |
                   ((unsigned)(v.z & 255) << 16) | ((unsigned)(v.w & 255) << 24);
  *(unsigned int*)&out[i] = b;
}

// ---------------- V transpose per head: vbT[h][d][j] = v[j][h*64+d] ------
__global__ __launch_bounds__(256) void vt_kernel(const ushort_t* __restrict__ v,
                                                 ushort_t* __restrict__ vbT) {
  int jt = blockIdx.x, h = blockIdx.y;
  __shared__ ushort_t L[64][72];
  int t = threadIdx.x;
  int r = t >> 2, c = (t & 3) * 16;
  const ushort_t* src = v + (size_t)(jt * 64 + r) * QS + h * 64 + c;
  *(uint4*)&L[r][c] = *(const uint4*)src;
  *(uint4*)&L[r][c + 8] = *(const uint4*)(src + 8);
  __syncthreads();
  int d = t >> 2, j0 = (t & 3) * 16;
  ushort_t tmp[16];
#pragma unroll
  for (int e = 0; e < 16; ++e) tmp[e] = L[j0 + e][d];
  ushort_t* dst = vbT + (size_t)(h * 64 + d) * NT + jt * 64 + j0;
  *(uint4*)dst = *(uint4*)&tmp[0];
  *(uint4*)(dst + 8) = *(uint4*)&tmp[8];
}

// ---------------- bf16 MFMA GEMM, 64x64 tile, BK=64, dbuf + gload_lds ----
// ACT: 0 none, 1 sigmoid, 2 gelu(tanh), 3 fused-QKVG epilogue
template <int ACT, bool OBF>
__global__ __launch_bounds__(256) void gemm64(
    const ushort_t* __restrict__ A, const ushort_t* __restrict__ Bt,
    const float* __restrict__ bias, const float* __restrict__ res,
    void* __restrict__ Cp, int K, int ldc, float scale) {
  __shared__ __align__(16) ushort_t As[2][4096];
  __shared__ __align__(16) ushort_t Bs[2][4096];
  int t = threadIdx.x;
  int i0 = blockIdx.y * 64, j0 = blockIdx.x * 64;
  int w = t >> 6, l = t & 63;
  int wm = w >> 1, wn = w & 1;
  int lr = l >> 4, lc = l & 15;
  int sr = t >> 3;
  int sc8 = ((t & 7) ^ (sr & 7)) * 8;
  const ushort_t* aS = A + (size_t)(i0 + sr) * K + sc8;
  const ushort_t* bS = Bt + (size_t)(j0 + sr) * K + sc8;
  int sA0 = (wm * 32 + lc) * 64 + ((lr ^ (lc & 7)) * 8);
  int sA1 = (wm * 32 + 16 + lc) * 64 + ((lr ^ (lc & 7)) * 8);
  int sB0 = (wn * 32 + lc) * 64 + ((lr ^ (lc & 7)) * 8);
  int sB1 = (wn * 32 + 16 + lc) * 64 + ((lr ^ (lc & 7)) * 8);

  fx4 acc[2][2] = {};

#define G64_STAGE(buf, k0)                                                   \
  {                                                                          \
    gload16(aS + (k0), &As[buf][t * 8]);                                     \
    gload16(aS + (k0) + (size_t)32 * K, &As[buf][2048 + t * 8]);             \
    gload16(bS + (k0), &Bs[buf][t * 8]);                                     \
    gload16(bS + (k0) + (size_t)32 * K, &Bs[buf][2048 + t * 8]);             \
  }

  G64_STAGE(0, 0);
  __syncthreads();
  int cur = 0;
  for (int k0 = 0; k0 < K; k0 += 64) {
    if (k0 + 64 < K) G64_STAGE(cur ^ 1, k0 + 64);
    const ushort_t* Ac = As[cur];
    const ushort_t* Bc = Bs[cur];
#pragma unroll
    for (int ks = 0; ks < 2; ++ks) {
      s8x a0 = *(const s8x*)&Ac[sA0 ^ (ks << 5)];
      s8x a1 = *(const s8x*)&Ac[sA1 ^ (ks << 5)];
      s8x b0 = *(const s8x*)&Bc[sB0 ^ (ks << 5)];
      s8x b1 = *(const s8x*)&Bc[sB1 ^ (ks << 5)];
      acc[0][0] = MFMA(a0, b0, acc[0][0]);
      acc[0][1] = MFMA(a0, b1, acc[0][1]);
      acc[1][0] = MFMA(a1, b0, acc[1][0]);
      acc[1][1] = MFMA(a1, b1, acc[1][1]);
    }
    __syncthreads();
    cur ^= 1;
  }
#undef G64_STAGE

#pragma unroll
  for (int ms = 0; ms < 2; ++ms) {
#pragma unroll
    for (int ns = 0; ns < 2; ++ns) {
#pragma unroll
      for (int r = 0; r < 4; ++r) {
        int i = i0 + wm * 32 + ms * 16 + lr * 4 + r;
        int j = j0 + wn * 32 + ns * 16 + lc;
        float o = acc[ms][ns][r] * scale;
        if (ACT == 3) {
          if (blockIdx.x < 8) o *= 0.18033688011112042f;  // 0.125*log2(e)
          if (blockIdx.x >= 24) {
            o += bias[j & 511];
            o = 1.0f / (1.0f + __expf(-o));
          }
        } else {
          if (bias) o += bias[j];
          if (ACT == 1) {
            o = 1.0f / (1.0f + __expf(-o));
          } else if (ACT == 2) {
            float xx = o;
            float c2 = 1.5957691216057308f * (xx + 0.044715f * xx * xx * xx);
            o = xx / (1.0f + __expf(-c2));  // == 0.5x(1+tanh(c))
          }
          if (res) o += res[(size_t)i * ldc + j];
        }
        if (OBF)
          ((ushort_t*)Cp)[(size_t)i * ldc + j] = f2b(o);
        else
          ((float*)Cp)[(size_t)i * ldc + j] = o;
      }
    }
  }
}

// ---------------- attention common helpers -------------------------------
__device__ __forceinline__ float rq_sel(const unsigned int* rqt,
                                        unsigned int idx) {
  unsigned int d01 = (idx & 2) ? rqt[1] : rqt[0];
  unsigned int d23 = (idx & 2) ? rqt[3] : rqt[2];
  unsigned int dd = (idx & 4) ? d23 : d01;
  unsigned int r = (idx & 1) ? (dd & 0xffff0000u) : (dd << 16);
  return __uint_as_float(r);
}

// ---------------- attn pass 1: per-row m,l -> lofs = m + log2(l) ---------
// K staging only (32KB LDS) -> 4 blocks/CU.
__global__ __launch_bounds__(256) void attn_ml_kernel(
    const ushort_t* __restrict__ xqkvg, const float* __restrict__ relk,
    const uchar_t* __restrict__ adm8, float* __restrict__ lofsb) {
  int f = blockIdx.y * (NT / 32) + blockIdx.x;
  int h = f & 7;
  int i0 = (f >> 3) * 32;
  int t = threadIdx.x, w = t >> 6, l = t & 63;
  int lr = l >> 4, lc = l & 15;
  int ig = w & 1, jh = w >> 1;
  int i_loc = ig * 16 + lc;
  int i = i0 + i_loc;

  __shared__ __align__(16) ushort_t Kd[2][2][4096];
  __shared__ float MLs[2][2][16][2];

  int stgo = ig * 2048;
  int srow = ig * 32 + (l >> 3);
  int kp8 = ((l & 7) ^ ((l >> 3) & 7)) * 8;
  const ushort_t* kSrc0 =
      xqkvg + 512 + (size_t)(jh * 64 + srow) * QS + h * 64 + kp8;
  const uchar_t* admp0 = adm8 + (size_t)i * NT + jh * 64 + lr * 4;

#define STAGE_K1(buf, tt)                                                    \
  {                                                                          \
    const ushort_t* ks_ = kSrc0 + (size_t)(tt) * 128 * QS;                   \
    gload16(ks_, Kd[buf][jh] + stgo);                                        \
    gload16(ks_ + (size_t)8 * QS, Kd[buf][jh] + stgo + 512);                 \
    gload16(ks_ + (size_t)16 * QS, Kd[buf][jh] + stgo + 1024);               \
    gload16(ks_ + (size_t)24 * QS, Kd[buf][jh] + stgo + 1536);               \
  }

  STAGE_K1(0, 0);

  const ushort_t* qp = xqkvg + (size_t)i * QS + h * 64 + lr * 8;
  s8x qf0 = *(const s8x*)qp;
  s8x qf1 = *(const s8x*)(qp + 32);

  unsigned int rqt[4];
  {
    const ushort_t* q0 = (const ushort_t*)&qf0;
    const ushort_t* q1 = (const ushort_t*)&qf1;
    float sp[8];
#pragma unroll
    for (int p = 0; p < 8; ++p) {
      const float* rp = relk + p * 64 + lr * 8;
      float s = 0.f;
#pragma unroll
      for (int e = 0; e < 8; ++e) s = fmaf(b2f(q0[e]), rp[e], s);
#pragma unroll
      for (int e = 0; e < 8; ++e) s = fmaf(b2f(q1[e]), rp[32 + e], s);
      s += __shfl_xor(s, 16);
      s += __shfl_xor(s, 32);
      sp[p] = s;
    }
#pragma unroll
    for (int j = 0; j < 4; ++j)
      rqt[j] = (unsigned int)f2b(sp[2 * j]) |
               ((unsigned int)f2b(sp[2 * j + 1]) << 16);
  }

  int sw = (lc & 7);
  int a_b0 = lc * 64 + ((lr ^ sw) << 3);
  int a_b1 = lc * 64 + (((4 + lr) ^ sw) << 3);

  float m_run = -1e30f, l_run = 0.f;
  __syncthreads();

  int cur = 0;
  for (int tt = 0; tt < 24; ++tt) {
    if (tt < 23) STAGE_K1(cur ^ 1, tt + 1);
    const ushort_t* KS = Kd[cur][jh];
    const uchar_t* admp = admp0 + tt * 128;
    fx4 sacc[4] = {};
#pragma unroll
    for (int ja = 0; ja < 4; ++ja) {
      s8x a0 = *(const s8x*)(KS + a_b0 + ja * 1024);
      s8x a1 = *(const s8x*)(KS + a_b1 + ja * 1024);
      sacc[ja] = MFMA(a0, qf0, sacc[ja]);
      sacc[ja] = MFMA(a1, qf1, sacc[ja]);
    }
    float sv[4][4];
    float tm = -1e30f;
#pragma unroll
    for (int ja = 0; ja < 4; ++ja) {
      unsigned int aw = *(const unsigned int*)(admp + ja * 16);
#pragma unroll
      for (int r = 0; r < 4; ++r) {
        float vv = sacc[ja][r] + rq_sel(rqt, (aw >> (8 * r)) & 7u);
        sv[ja][r] = vv;
        tm = fmaxf(tm, vv);
      }
    }
    float mn = fmaxf(m_run, tm);
    float sum = 0.f;
#pragma unroll
    for (int ja = 0; ja < 4; ++ja)
#pragma unroll
      for (int r = 0; r < 4; ++r) sum += EX2(sv[ja][r] - mn);
    l_run = l_run * EX2(m_run - mn) + sum;
    m_run = mn;
    __syncthreads();
    cur ^= 1;
  }
#undef STAGE_K1

#pragma unroll
  for (int off = 16; off <= 32; off <<= 1) {
    float mo = __shfl_xor(m_run, off), lo = __shfl_xor(l_run, off);
    float mn = fmaxf(m_run, mo);
    l_run = l_run * EX2(m_run - mn) + lo * EX2(mo - mn);
    m_run = mn;
  }
  if (l < 16) {
    MLs[jh][ig][lc][0] = m_run;
    MLs[jh][ig][lc][1] = l_run;
  }
  __syncthreads();
  if (jh == 0 && l < 16) {
    float mo = MLs[1][ig][lc][0], lo = MLs[1][ig][lc][1];
    float mn = fmaxf(m_run, mo);
    l_run = l_run * EX2(m_run - mn) + lo * EX2(mo - mn);
    lofsb[(size_t)h * NT + i] = mn + __log2f(l_run);
  }
}

// ---------------- attn pass 2: P = exp2(S - lofs); att out + PV ----------
__global__ __launch_bounds__(256) void attn_pv_kernel(
    const ushort_t* __restrict__ xqkvg, const ushort_t* __restrict__ vbT,
    const float* __restrict__ relk, const uchar_t* __restrict__ adm8,
    const float* __restrict__ lofsb, float* __restrict__ att,
    ushort_t* __restrict__ av) {
  int f = blockIdx.y * (NT / 32) + blockIdx.x;
  int h = f & 7;
  int i0 = (f >> 3) * 32;
  int t = threadIdx.x, w = t >> 6, l = t & 63;
  int lr = l >> 4, lc = l & 15;
  int ig = w & 1, jh = w >> 1;
  int i_loc = ig * 16 + lc;
  int i = i0 + i_loc;

  __shared__ __align__(16) ushort_t Kd[2][2][4096];
  __shared__ __align__(16) ushort_t Vd[2][2][4096];
  __shared__ __align__(16) ushort_t Ps[2][2048];

  int stgo = ig * 2048;
  int srow = ig * 32 + (l >> 3);
  int kp8 = ((l & 7) ^ ((l >> 3) & 7)) * 8;
  const ushort_t* kSrc0 =
      xqkvg + 512 + (size_t)(jh * 64 + srow) * QS + h * 64 + kp8;
  const ushort_t* vSrc0 = vbT + (size_t)(h * 64 + srow) * NT + jh * 64 + kp8;
  const uchar_t* admp0 = adm8 + (size_t)i * NT + jh * 64 + lr * 4;

#define STAGE_K2(buf, tt)                                                    \
  {                                                                          \
    const ushort_t* ks_ = kSrc0 + (size_t)(tt) * 128 * QS;                   \
    gload16(ks_, Kd[buf][jh] + stgo);                                        \
    gload16(ks_ + (size_t)8 * QS, Kd[buf][jh] + stgo + 512);                 \
    gload16(ks_ + (size_t)16 * QS, Kd[buf][jh] + stgo + 1024);               \
    gload16(ks_ + (size_t)24 * QS, Kd[buf][jh] + stgo + 1536);               \
  }
#define STAGE_V2(buf, tt)                                                    \
  {                                                                          \
    const ushort_t* vs_ = vSrc0 + (tt) * 128;                                \
    gload16(vs_, Vd[buf][jh] + stgo);                                        \
    gload16(vs_ + (size_t)8 * NT, Vd[buf][jh] + stgo + 512);                 \
    gload16(vs_ + (size_t)16 * NT, Vd[buf][jh] + stgo + 1024);               \
    gload16(vs_ + (size_t)24 * NT, Vd[buf][jh] + stgo + 1536);               \
  }

  STAGE_K2(0, 0);
  STAGE_V2(0, 0);

  const ushort_t* qp = xqkvg + (size_t)i * QS + h * 64 + lr * 8;
  s8x qf0 = *(const s8x*)qp;
  s8x qf1 = *(const s8x*)(qp + 32);
  float lofs = lofsb[(size_t)h * NT + i];

  unsigned int rqt[4];
  {
    const ushort_t* q0 = (const ushort_t*)&qf0;
    const ushort_t* q1 = (const ushort_t*)&qf1;
    float sp[8];
#pragma unroll
    for (int p = 0; p < 8; ++p) {
      const float* rp = relk + p * 64 + lr * 8;
      float s = 0.f;
#pragma unroll
      for (int e = 0; e < 8; ++e) s = fmaf(b2f(q0[e]), rp[e], s);
#pragma unroll
      for (int e = 0; e < 8; ++e) s = fmaf(b2f(q1[e]), rp[32 + e], s);
      s += __shfl_xor(s, 16);
      s += __shfl_xor(s, 32);
      sp[p] = s;
    }
#pragma unroll
    for (int j = 0; j < 4; ++j)
      rqt[j] = (unsigned int)f2b(sp[2 * j]) |
               ((unsigned int)f2b(sp[2 * j + 1]) << 16);
  }

  int sw = (lc & 7);
  int a_b0 = lc * 64 + ((lr ^ sw) << 3);
  int a_b1 = lc * 64 + (((4 + lr) ^ sw) << 3);
  int pb0 = i_loc * 64 + ((lr ^ sw) << 3);
  int pb1 = i_loc * 64 + (((4 + lr) ^ sw) << 3);
  int swz8 = sw << 3;

  fx4 oacc[4] = {};
  float* attb = att + ((size_t)h * NT + i0) * NT;
  ushort_t* PS = Ps[jh];
  int jh64 = jh * 64;
  __syncthreads();  // tile0 staged

  int cur = 0;
  for (int tt = 0; tt < 24; ++tt) {
    if (tt < 23) {
      STAGE_K2(cur ^ 1, tt + 1);
      STAGE_V2(cur ^ 1, tt + 1);
    }
    const ushort_t* KS = Kd[cur][jh];
    const ushort_t* VS = Vd[cur][jh];
    const uchar_t* admp = admp0 + tt * 128;
    fx4 sacc[4] = {};
#pragma unroll
    for (int ja = 0; ja < 4; ++ja) {
      s8x a0 = *(const s8x*)(KS + a_b0 + ja * 1024);
      s8x a1 = *(const s8x*)(KS + a_b1 + ja * 1024);
      sacc[ja] = MFMA(a0, qf0, sacc[ja]);
      sacc[ja] = MFMA(a1, qf1, sacc[ja]);
    }
#pragma unroll
    for (int ja = 0; ja < 4; ++ja) {
      unsigned int aw = *(const unsigned int*)(admp + ja * 16);
      float p0 = EX2(sacc[ja][0] + rq_sel(rqt, aw & 7u) - lofs);
      float p1 = EX2(sacc[ja][1] + rq_sel(rqt, (aw >> 8) & 7u) - lofs);
      float p2 = EX2(sacc[ja][2] + rq_sel(rqt, (aw >> 16) & 7u) - lofs);
      float p3 = EX2(sacc[ja][3] + rq_sel(rqt, (aw >> 24) & 7u) - lofs);
      unsigned int w01 = (unsigned int)f2b(p0) | ((unsigned int)f2b(p1) << 16);
      unsigned int w23 = (unsigned int)f2b(p2) | ((unsigned int)f2b(p3) << 16);
      int cb = ja * 16 + lr * 4;
      *(unsigned int*)&PS[i_loc * 64 + (cb ^ swz8)] = w01;
      *(unsigned int*)&PS[i_loc * 64 + ((cb + 2) ^ swz8)] = w23;
    }
    // att copy-out: SAME-WAVE rows only (no barrier needed); drains under PV
    {
      int uu = ig * 64 + l;
      int row = uu >> 2, cs = (uu & 3) * 16;
      int rsw = (row & 7) << 3;
      uint4 A_ = *(const uint4*)&PS[row * 64 + (cs ^ rsw)];
      uint4 B_ = *(const uint4*)&PS[row * 64 + ((cs + 8) ^ rsw)];
      const ushort_t* ap = (const ushort_t*)&A_;
      const ushort_t* bp = (const ushort_t*)&B_;
      float* op = attb + (size_t)row * NT + tt * 128 + jh64 + cs;
      f4 o0 = {b2f(ap[0]), b2f(ap[1]), b2f(ap[2]), b2f(ap[3])};
      f4 o1 = {b2f(ap[4]), b2f(ap[5]), b2f(ap[6]), b2f(ap[7])};
      f4 o2 = {b2f(bp[0]), b2f(bp[1]), b2f(bp[2]), b2f(bp[3])};
      f4 o3 = {b2f(bp[4]), b2f(bp[5]), b2f(bp[6]), b2f(bp[7])};
      *(f4*)(op + 0) = o0;
      *(f4*)(op + 4) = o1;
      *(f4*)(op + 8) = o2;
      *(f4*)(op + 12) = o3;
    }
    // PV: Ot[d][i] += Vt[d][j] * P[i][j]
#pragma unroll
    for (int ks = 0; ks < 2; ++ks) {
      s8x pf = *(const s8x*)(PS + (ks == 0 ? pb0 : pb1));
#pragma unroll
      for (int nd = 0; nd < 4; ++nd) {
        s8x vf = *(const s8x*)(VS + (ks == 0 ? a_b0 : a_b1) + nd * 1024);
        oacc[nd] = MFMA(vf, pf, oacc[nd]);
      }
    }
    __syncthreads();
    cur ^= 1;
  }
#undef STAGE_K2
#undef STAGE_V2

  // merge O across j-halves via Ps (bf16), apply gate, write av
  ushort_t* PsF = &Ps[0][0];
  int swzO = (i_loc & 7) << 3;
  if (jh == 1) {
#pragma unroll
    for (int nd = 0; nd < 4; ++nd) {
      int d0 = nd * 16 + lr * 4;
      unsigned int lo = (unsigned int)f2b(oacc[nd][0]) |
                        ((unsigned int)f2b(oacc[nd][1]) << 16);
      unsigned int hi = (unsigned int)f2b(oacc[nd][2]) |
                        ((unsigned int)f2b(oacc[nd][3]) << 16);
      uint2 pk = {lo, hi};
      *(uint2*)&PsF[i_loc * 64 + (d0 ^ swzO)] = pk;
    }
  }
  __syncthreads();
  if (jh == 0) {
    const ushort_t* gp = xqkvg + (size_t)i * QS + 1536 + h * 64;
#pragma unroll
    for (int nd = 0; nd < 4; ++nd) {
      int d0 = nd * 16 + lr * 4;
      uint2 pk = *(const uint2*)&PsF[i_loc * 64 + (d0 ^ swzO)];
      const ushort_t* pp = (const ushort_t*)&pk;
      uint2 gk = *(const uint2*)(gp + d0);
      const ushort_t* gg = (const ushort_t*)&gk;
      ushort_t ot[4];
#pragma unroll
      for (int r = 0; r < 4; ++r)
        ot[r] = f2b((oacc[nd][r] + b2f(pp[r])) * b2f(gg[r]));
      *(uint2*)&av[(size_t)i * DIM + h * 64 + d0] = *(uint2*)ot;
    }
  }
}

extern "C" void kernel_launch(void* const* d_in, const int* in_sizes, int n_in,
                              void* d_out, int out_size, void* d_ws,
                              size_t ws_size, hipStream_t stream) {
  const float* x_in = (const float*)d_in[0];
  const int* adm = (const int*)d_in[1];
  const float* ln_att_s = (const float*)d_in[2];
  const float* ln_att_b = (const float*)d_in[3];
  const float* Wq = (const float*)d_in[4];
  const float* Wk = (const float*)d_in[5];
  const float* Wv = (const float*)d_in[6];
  const float* rel_k = (const float*)d_in[7];
  const float* Wg = (const float*)d_in[8];
  const float* bg = (const float*)d_in[9];
  const float* Wo = (const float*)d_in[10];
  const float* bo = (const float*)d_in[11];
  const float* ln_ff_s = (const float*)d_in[12];
  const float* ln_ff_b = (const float*)d_in[13];
  const float* W1 = (const float*)d_in[14];
  const float* b1 = (const float*)d_in[15];
  const float* W2 = (const float*)d_in[16];
  const float* b2 = (const float*)d_in[17];
  float* out = (float*)d_out;

  const size_t ND = (size_t)NT * DIM;
  char* ws = (char*)d_ws;
  float* x_cur = (float*)ws;                    // 6.29 MB
  float* y = (float*)(ws + 6291456);            // 6.29 MB
  ushort_t* xqkvg = (ushort_t*)(ws + 12582912); // 12.58 MB [3072][2048]
  ushort_t* avb = (ushort_t*)(ws + 25165824);   // 3.15 MB
  ushort_t* xnb = (ushort_t*)(ws + 28311552);   // 3.15 MB
  ushort_t* vbT = (ushort_t*)(ws + 31457280);   // 3.15 MB [8][64][3072]
  uchar_t* adm8 = (uchar_t*)(ws + 34603008);    // 9.44 MB
  float* lofsb = (float*)(ws + 44040192);       // 98 KB [8][3072]
  ushort_t* Wt = (ushort_t*)(ws + 44138496);    // 14.2 MB (3 layers)
  ushort_t* h1b = xqkvg;                        // FFN hidden aliases xqkvg

  adm8_kernel<<<(NT * NT) / 1024, 256, 0, stream>>>(adm, adm8);
  wprep_kernel<<<dim3(576, 3), 256, 0, stream>>>(Wq, Wk, Wv, Wg, Wo, W1, W2,
                                                 Wt);

  dim3 gQKVG(32, NT / 64);
  dim3 gA(8, NT / 64);
  dim3 gF1(16, NT / 64);
  dim3 gATT(NT / 32, NH);

  for (int n = 0; n < NL; ++n) {
    float* att = out + ND + (size_t)n * NH * NT * NT;
    const float* xprev = (n == 0) ? x_in : x_cur;   // residual stream input
    float* xout = (n == NL - 1) ? out : x_cur;      // final layer -> d_out
    ushort_t* Wtl = Wt + (size_t)n * 2359296;

    ln_bf16_kernel<<<NT, 256, 0, stream>>>(xprev, ln_att_s + n * DIM,
                                           ln_att_b + n * DIM, xnb);
    // fused QKVG: cols [0,512)=q(scaled), [512,1024)=k, [1024,1536)=v,
    // [1536,2048)=sigmoid(g+bg)
    gemm64<3, true><<<gQKVG, 256, 0, stream>>>(xnb, Wtl, bg + n * DIM, nullptr,
                                               xqkvg, DIM, QS, 1.0f);
    vt_kernel<<<dim3(NT / 64, NH), 256, 0, stream>>>(xqkvg + 1024, vbT);
    attn_ml_kernel<<<gATT, 256, 0, stream>>>(xqkvg, rel_k + n * PKN * DKH,
                                             adm8, lofsb);
    attn_pv_kernel<<<gATT, 256, 0, stream>>>(
        xqkvg, vbT, rel_k + n * PKN * DKH, adm8, lofsb, att, avb);
    // y = x + (av*gate)@Wo + bo   (gate already folded into avb)
    gemm64<0, false><<<gA, 256, 0, stream>>>(avb, Wtl + 1048576, bo + n * DIM,
                                             xprev, y, DIM, DIM, 1.0f);
    ln_bf16_kernel<<<NT, 256, 0, stream>>>(y, ln_ff_s + n * DIM,
                                           ln_ff_b + n * DIM, xnb);
    gemm64<2, true><<<gF1, 256, 0, stream>>>(xnb, Wtl + 1310720, b1 + n * D2,
                                             nullptr, h1b, DIM, D2, 1.0f);
    // x_new = x_old + ff  (last layer writes straight to d_out)
    gemm64<0, false><<<gA, 256, 0, stream>>>(h1b, Wtl + 1835008, b2 + n * DIM,
                                             xprev, xout, D2, DIM, 1.0f);
  }
}

// Round 10
// 980.891 us; speedup vs baseline: 1.4488x; 1.0306x over previous
//
#include <hip/hip_runtime.h>
#include <math.h>

#define NT 3072
#define DIM 512
#define NH 8
#define DKH 64
#define PKN 8
#define D2 1024
#define NL 3
#define QS 2048  // row stride of fused qkvg buffer

typedef float4 f4;
typedef unsigned short ushort_t;
typedef unsigned char uchar_t;
typedef __attribute__((ext_vector_type(8))) short s8x;
typedef __attribute__((ext_vector_type(4))) float fx4;

#define MFMA(a, b, c) __builtin_amdgcn_mfma_f32_16x16x32_bf16(a, b, c, 0, 0, 0)
#define EX2(x) __builtin_amdgcn_exp2f(x)

__device__ __forceinline__ float b2f(ushort_t u) {
  union { unsigned int x; float f; } c;
  c.x = (unsigned int)u << 16;
  return c.f;
}
__device__ __forceinline__ ushort_t f2b(float f) {
  union { float f; unsigned int x; } c;
  c.f = f;
  unsigned int r = (c.x + 0x7FFFu + ((c.x >> 16) & 1u)) >> 16;
  return (ushort_t)r;
}
__device__ __forceinline__ float wred_sum(float v) {
#pragma unroll
  for (int off = 32; off > 0; off >>= 1) v += __shfl_xor(v, off);
  return v;
}
__device__ __forceinline__ void gload16(const ushort_t* g, ushort_t* l) {
  __builtin_amdgcn_global_load_lds(
      (const __attribute__((address_space(1))) unsigned int*)(const void*)g,
      (__attribute__((address_space(3))) unsigned int*)(void*)l, 16, 0, 0);
}

// ---------------- LayerNorm -> bf16 ----------------
__global__ __launch_bounds__(256) void ln_bf16_kernel(
    const float* __restrict__ x, const float* __restrict__ s,
    const float* __restrict__ b, ushort_t* __restrict__ out) {
  int row = blockIdx.x;
  const float* xr = x + (size_t)row * DIM;
  int t = threadIdx.x;
  float v0 = xr[t], v1 = xr[t + 256];
  float sum = wred_sum(v0 + v1);
  float sq = wred_sum(v0 * v0 + v1 * v1);
  __shared__ float ss[4], s2[4];
  if ((t & 63) == 0) { ss[t >> 6] = sum; s2[t >> 6] = sq; }
  __syncthreads();
  float tot = ss[0] + ss[1] + ss[2] + ss[3];
  float tot2 = s2[0] + s2[1] + s2[2] + s2[3];
  float mean = tot * (1.0f / DIM);
  float var = tot2 * (1.0f / DIM) - mean * mean;
  float inv = rsqrtf(var + 1e-6f);
  ushort_t* orow = out + (size_t)row * DIM;
  orow[t] = f2b((v0 - mean) * inv * s[t] + b[t]);
  orow[t + 256] = f2b((v1 - mean) * inv * s[t + 256] + b[t + 256]);
}

// ---------------- per-layer weight transpose+convert (all 3 layers) ------
__device__ __forceinline__ void tconv_body(const float* __restrict__ W,
                                           ushort_t* __restrict__ Wt, int K,
                                           int Nc, int tx, int ty) {
  __shared__ float Ls[64][65];
  int t = threadIdx.x;
  int n0 = tx * 64, k0 = ty * 64;
  int rr = t >> 4, cc = (t & 15) * 4;
#pragma unroll
  for (int p = 0; p < 4; ++p) {
    f4 v = *(const f4*)&W[(size_t)(k0 + rr + p * 16) * Nc + n0 + cc];
    Ls[rr + p * 16][cc + 0] = v.x;
    Ls[rr + p * 16][cc + 1] = v.y;
    Ls[rr + p * 16][cc + 2] = v.z;
    Ls[rr + p * 16][cc + 3] = v.w;
  }
  __syncthreads();
  int nr = t >> 2, kc = (t & 3) * 16;
  ushort_t tmp[16];
#pragma unroll
  for (int e = 0; e < 16; ++e) tmp[e] = f2b(Ls[kc + e][nr]);
  ushort_t* dst = &Wt[(size_t)(n0 + nr) * K + k0 + kc];
  *(uint4*)dst = *(uint4*)&tmp[0];
  *(uint4*)(dst + 8) = *(uint4*)&tmp[8];
}

__global__ __launch_bounds__(256) void wprep_kernel(
    const float* __restrict__ Wq, const float* __restrict__ Wk,
    const float* __restrict__ Wv, const float* __restrict__ Wg,
    const float* __restrict__ Wo, const float* __restrict__ W1,
    const float* __restrict__ W2, ushort_t* __restrict__ Wt) {
  int n = blockIdx.y;
  size_t wo5 = (size_t)n * 262144;
  ushort_t* Wtl = Wt + (size_t)n * 2359296;
  int bid = blockIdx.x;
  if (bid < 320) {
    int job = bid >> 6, tile = bid & 63;
    const float* src = job == 0 ? Wq + wo5 : job == 1 ? Wk + wo5
                       : job == 2 ? Wv + wo5 : job == 3 ? Wg + wo5 : Wo + wo5;
    tconv_body(src, Wtl + (size_t)job * 262144, 512, 512, tile & 7, tile >> 3);
  } else if (bid < 448) {
    int tile = bid - 320;
    tconv_body(W1 + (size_t)n * 524288, Wtl + 1310720, 512, 1024, tile & 15,
               tile >> 4);
  } else {
    int tile = bid - 448;
    tconv_body(W2 + (size_t)n * 524288, Wtl + 1835008, 1024, 512, tile & 7,
               tile >> 3);
  }
}

// ---------------- adm int32 -> int8 ----------------
__global__ __launch_bounds__(256) void adm8_kernel(const int* __restrict__ adm,
                                                   uchar_t* __restrict__ out) {
  size_t i = ((size_t)blockIdx.x * 256 + threadIdx.x) * 4;
  int4 v = *(const int4*)&adm[i];
  unsigned int b = (unsigned)(v.x & 255) | ((unsigned)(v.y & 255) << 8) |
                   ((unsigned)(v.z & 255) << 16) | ((unsigned)(v.w & 255) << 24);
  *(unsigned int*)&out[i] = b;
}

// ---------------- bf16 MFMA GEMM, 64x64 tile, BK=64, dbuf + gload_lds ----
// ACT: 0 none, 1 sigmoid, 2 gelu(tanh), 3 fused-QKVG epilogue
// ACT==3 extra: V-column blocks (bx 16..23) also emit the per-head V
// transpose into vt_out (vbT[h][d][token]) via an LDS transpose.
template <int ACT, bool OBF>
__global__ __launch_bounds__(256) void gemm64(
    const ushort_t* __restrict__ A, const ushort_t* __restrict__ Bt,
    const float* __restrict__ bias, const float* __restrict__ res,
    void* __restrict__ Cp, int K, int ldc, float scale,
    ushort_t* __restrict__ vt_out) {
  __shared__ __align__(16) ushort_t As[2][4096];
  __shared__ __align__(16) ushort_t Bs[2][4096];
  int t = threadIdx.x;
  int i0 = blockIdx.y * 64, j0 = blockIdx.x * 64;
  int w = t >> 6, l = t & 63;
  int wm = w >> 1, wn = w & 1;
  int lr = l >> 4, lc = l & 15;
  int sr = t >> 3;
  int sc8 = ((t & 7) ^ (sr & 7)) * 8;
  const ushort_t* aS = A + (size_t)(i0 + sr) * K + sc8;
  const ushort_t* bS = Bt + (size_t)(j0 + sr) * K + sc8;
  int sA0 = (wm * 32 + lc) * 64 + ((lr ^ (lc & 7)) * 8);
  int sA1 = (wm * 32 + 16 + lc) * 64 + ((lr ^ (lc & 7)) * 8);
  int sB0 = (wn * 32 + lc) * 64 + ((lr ^ (lc & 7)) * 8);
  int sB1 = (wn * 32 + 16 + lc) * 64 + ((lr ^ (lc & 7)) * 8);

  fx4 acc[2][2] = {};

#define G64_STAGE(buf, k0)                                                   \
  {                                                                          \
    gload16(aS + (k0), &As[buf][t * 8]);                                     \
    gload16(aS + (k0) + (size_t)32 * K, &As[buf][2048 + t * 8]);             \
    gload16(bS + (k0), &Bs[buf][t * 8]);                                     \
    gload16(bS + (k0) + (size_t)32 * K, &Bs[buf][2048 + t * 8]);             \
  }

  G64_STAGE(0, 0);
  __syncthreads();
  int cur = 0;
  for (int k0 = 0; k0 < K; k0 += 64) {
    if (k0 + 64 < K) G64_STAGE(cur ^ 1, k0 + 64);
    const ushort_t* Ac = As[cur];
    const ushort_t* Bc = Bs[cur];
#pragma unroll
    for (int ks = 0; ks < 2; ++ks) {
      s8x a0 = *(const s8x*)&Ac[sA0 ^ (ks << 5)];
      s8x a1 = *(const s8x*)&Ac[sA1 ^ (ks << 5)];
      s8x b0 = *(const s8x*)&Bc[sB0 ^ (ks << 5)];
      s8x b1 = *(const s8x*)&Bc[sB1 ^ (ks << 5)];
      acc[0][0] = MFMA(a0, b0, acc[0][0]);
      acc[0][1] = MFMA(a0, b1, acc[0][1]);
      acc[1][0] = MFMA(a1, b0, acc[1][0]);
      acc[1][1] = MFMA(a1, b1, acc[1][1]);
    }
    __syncthreads();
    cur ^= 1;
  }
#undef G64_STAGE

  bool isV = (ACT == 3) && (blockIdx.x >= 16) && (blockIdx.x < 24);
  ushort_t* TrS = &As[0][0];  // reuse staging LDS for the V transpose

#pragma unroll
  for (int ms = 0; ms < 2; ++ms) {
#pragma unroll
    for (int ns = 0; ns < 2; ++ns) {
      ushort_t vtmp[4];
#pragma unroll
      for (int r = 0; r < 4; ++r) {
        int i = i0 + wm * 32 + ms * 16 + lr * 4 + r;
        int j = j0 + wn * 32 + ns * 16 + lc;
        float o = acc[ms][ns][r] * scale;
        if (ACT == 3) {
          if (blockIdx.x < 8) o *= 0.18033688011112042f;  // 0.125*log2(e)
          if (blockIdx.x >= 24) {
            o += bias[j & 511];
            o = 1.0f / (1.0f + __expf(-o));
          }
        } else {
          if (bias) o += bias[j];
          if (ACT == 1) {
            o = 1.0f / (1.0f + __expf(-o));
          } else if (ACT == 2) {
            float xx = o;
            float c2 = 1.5957691216057308f * (xx + 0.044715f * xx * xx * xx);
            o = xx / (1.0f + __expf(-c2));  // == 0.5x(1+tanh(c))
          }
          if (res) o += res[(size_t)i * ldc + j];
        }
        if (OBF) {
          ushort_t ob = f2b(o);
          ((ushort_t*)Cp)[(size_t)i * ldc + j] = ob;
          if (isV) vtmp[r] = ob;
        } else {
          ((float*)Cp)[(size_t)i * ldc + j] = o;
        }
      }
      if (isV) {
        int jl = wn * 32 + ns * 16 + lc;          // head-dim within tile
        int ib = wm * 32 + ms * 16 + lr * 4;      // token within tile
        *(uint2*)&TrS[jl * 64 + (ib ^ ((jl & 7) << 3))] = *(uint2*)vtmp;
      }
    }
  }
  if (isV) {
    __syncthreads();
    int d = t >> 2, c = (t & 3) * 16;
    int sw8 = (d & 7) << 3;
    uint4 A_ = *(const uint4*)&TrS[d * 64 + (c ^ sw8)];
    uint4 B_ = *(const uint4*)&TrS[d * 64 + ((c + 8) ^ sw8)];
    ushort_t* dst =
        vt_out + (size_t)((blockIdx.x - 16) * 64 + d) * NT + i0 + c;
    *(uint4*)dst = A_;
    *(uint4*)(dst + 8) = B_;
  }
}

// ---------------- attention common helpers -------------------------------
__device__ __forceinline__ float rq_sel(const unsigned int* rqt,
                                        unsigned int idx) {
  unsigned int d01 = (idx & 2) ? rqt[1] : rqt[0];
  unsigned int d23 = (idx & 2) ? rqt[3] : rqt[2];
  unsigned int dd = (idx & 4) ? d23 : d01;
  unsigned int r = (idx & 1) ? (dd & 0xffff0000u) : (dd << 16);
  return __uint_as_float(r);
}

// ---------------- attn pass 1: per-row l -> lofs = log2(l) ---------------
// No max-tracking: |S| <= |q||k|*0.18 <= ~22 (Cauchy-Schwarz on 64-dim
// unit-var rows), so sum(exp2(S)) <= ~1e8 -- far from fp32 overflow, and
// P = exp2(S - log2 l) <= 1 exactly as with max subtraction.
// K staging only (32KB LDS) -> 4 blocks/CU.
__global__ __launch_bounds__(256) void attn_ml_kernel(
    const ushort_t* __restrict__ xqkvg, const float* __restrict__ relk,
    const uchar_t* __restrict__ adm8, float* __restrict__ lofsb) {
  int f = blockIdx.y * (NT / 32) + blockIdx.x;
  int h = f & 7;
  int i0 = (f >> 3) * 32;
  int t = threadIdx.x, w = t >> 6, l = t & 63;
  int lr = l >> 4, lc = l & 15;
  int ig = w & 1, jh = w >> 1;
  int i_loc = ig * 16 + lc;
  int i = i0 + i_loc;

  __shared__ __align__(16) ushort_t Kd[2][2][4096];
  __shared__ float MLs[2][2][16];

  int stgo = ig * 2048;
  int srow = ig * 32 + (l >> 3);
  int kp8 = ((l & 7) ^ ((l >> 3) & 7)) * 8;
  const ushort_t* kSrc0 =
      xqkvg + 512 + (size_t)(jh * 64 + srow) * QS + h * 64 + kp8;
  const uchar_t* admp0 = adm8 + (size_t)i * NT + jh * 64 + lr * 4;

#define STAGE_K1(buf, tt)                                                    \
  {                                                                          \
    const ushort_t* ks_ = kSrc0 + (size_t)(tt) * 128 * QS;                   \
    gload16(ks_, Kd[buf][jh] + stgo);                                        \
    gload16(ks_ + (size_t)8 * QS, Kd[buf][jh] + stgo + 512);                 \
    gload16(ks_ + (size_t)16 * QS, Kd[buf][jh] + stgo + 1024);               \
    gload16(ks_ + (size_t)24 * QS, Kd[buf][jh] + stgo + 1536);               \
  }

  STAGE_K1(0, 0);

  const ushort_t* qp = xqkvg + (size_t)i * QS + h * 64 + lr * 8;
  s8x qf0 = *(const s8x*)qp;
  s8x qf1 = *(const s8x*)(qp + 32);

  unsigned int rqt[4];
  {
    const ushort_t* q0 = (const ushort_t*)&qf0;
    const ushort_t* q1 = (const ushort_t*)&qf1;
    float sp[8];
#pragma unroll
    for (int p = 0; p < 8; ++p) {
      const float* rp = relk + p * 64 + lr * 8;
      float s = 0.f;
#pragma unroll
      for (int e = 0; e < 8; ++e) s = fmaf(b2f(q0[e]), rp[e], s);
#pragma unroll
      for (int e = 0; e < 8; ++e) s = fmaf(b2f(q1[e]), rp[32 + e], s);
      s += __shfl_xor(s, 16);
      s += __shfl_xor(s, 32);
      sp[p] = s;
    }
#pragma unroll
    for (int j = 0; j < 4; ++j)
      rqt[j] = (unsigned int)f2b(sp[2 * j]) |
               ((unsigned int)f2b(sp[2 * j + 1]) << 16);
  }

  int sw = (lc & 7);
  int a_b0 = lc * 64 + ((lr ^ sw) << 3);
  int a_b1 = lc * 64 + (((4 + lr) ^ sw) << 3);

  float l_run = 0.f;
  __syncthreads();

  int cur = 0;
  for (int tt = 0; tt < 24; ++tt) {
    if (tt < 23) STAGE_K1(cur ^ 1, tt + 1);
    const ushort_t* KS = Kd[cur][jh];
    const uchar_t* admp = admp0 + tt * 128;
    fx4 sacc[4] = {};
#pragma unroll
    for (int ja = 0; ja < 4; ++ja) {
      s8x a0 = *(const s8x*)(KS + a_b0 + ja * 1024);
      s8x a1 = *(const s8x*)(KS + a_b1 + ja * 1024);
      sacc[ja] = MFMA(a0, qf0, sacc[ja]);
      sacc[ja] = MFMA(a1, qf1, sacc[ja]);
    }
    float sum = 0.f;
#pragma unroll
    for (int ja = 0; ja < 4; ++ja) {
      unsigned int aw = *(const unsigned int*)(admp + ja * 16);
#pragma unroll
      for (int r = 0; r < 4; ++r)
        sum += EX2(sacc[ja][r] + rq_sel(rqt, (aw >> (8 * r)) & 7u));
    }
    l_run += sum;
    __syncthreads();
    cur ^= 1;
  }
#undef STAGE_K1

  l_run += __shfl_xor(l_run, 16);
  l_run += __shfl_xor(l_run, 32);
  if (l < 16) MLs[jh][ig][lc] = l_run;
  __syncthreads();
  if (jh == 0 && l < 16)
    lofsb[(size_t)h * NT + i] = __log2f(l_run + MLs[1][ig][lc]);
}

// ---------------- attn pass 2: P = exp2(S - lofs); att out + PV ----------
__global__ __launch_bounds__(256) void attn_pv_kernel(
    const ushort_t* __restrict__ xqkvg, const ushort_t* __restrict__ vbT,
    const float* __restrict__ relk, const uchar_t* __restrict__ adm8,
    const float* __restrict__ lofsb, float* __restrict__ att,
    ushort_t* __restrict__ av) {
  int f = blockIdx.y * (NT / 32) + blockIdx.x;
  int h = f & 7;
  int i0 = (f >> 3) * 32;
  int t = threadIdx.x, w = t >> 6, l = t & 63;
  int lr = l >> 4, lc = l & 15;
  int ig = w & 1, jh = w >> 1;
  int i_loc = ig * 16 + lc;
  int i = i0 + i_loc;

  __shared__ __align__(16) ushort_t Kd[2][2][4096];
  __shared__ __align__(16) ushort_t Vd[2][2][4096];
  __shared__ __align__(16) ushort_t Ps[2][2048];

  int stgo = ig * 2048;
  int srow = ig * 32 + (l >> 3);
  int kp8 = ((l & 7) ^ ((l >> 3) & 7)) * 8;
  const ushort_t* kSrc0 =
      xqkvg + 512 + (size_t)(jh * 64 + srow) * QS + h * 64 + kp8;
  const ushort_t* vSrc0 = vbT + (size_t)(h * 64 + srow) * NT + jh * 64 + kp8;
  const uchar_t* admp0 = adm8 + (size_t)i * NT + jh * 64 + lr * 4;

#define STAGE_K2(buf, tt)                                                    \
  {                                                                          \
    const ushort_t* ks_ = kSrc0 + (size_t)(tt) * 128 * QS;                   \
    gload16(ks_, Kd[buf][jh] + stgo);                                        \
    gload16(ks_ + (size_t)8 * QS, Kd[buf][jh] + stgo + 512);                 \
    gload16(ks_ + (size_t)16 * QS, Kd[buf][jh] + stgo + 1024);               \
    gload16(ks_ + (size_t)24 * QS, Kd[buf][jh] + stgo + 1536);               \
  }
#define STAGE_V2(buf, tt)                                                    \
  {                                                                          \
    const ushort_t* vs_ = vSrc0 + (tt) * 128;                                \
    gload16(vs_, Vd[buf][jh] + stgo);                                        \
    gload16(vs_ + (size_t)8 * NT, Vd[buf][jh] + stgo + 512);                 \
    gload16(vs_ + (size_t)16 * NT, Vd[buf][jh] + stgo + 1024);               \
    gload16(vs_ + (size_t)24 * NT, Vd[buf][jh] + stgo + 1536);               \
  }

  STAGE_K2(0, 0);
  STAGE_V2(0, 0);

  const ushort_t* qp = xqkvg + (size_t)i * QS + h * 64 + lr * 8;
  s8x qf0 = *(const s8x*)qp;
  s8x qf1 = *(const s8x*)(qp + 32);
  float lofs = lofsb[(size_t)h * NT + i];

  unsigned int rqt[4];
  {
    const ushort_t* q0 = (const ushort_t*)&qf0;
    const ushort_t* q1 = (const ushort_t*)&qf1;
    float sp[8];
#pragma unroll
    for (int p = 0; p < 8; ++p) {
      const float* rp = relk + p * 64 + lr * 8;
      float s = 0.f;
#pragma unroll
      for (int e = 0; e < 8; ++e) s = fmaf(b2f(q0[e]), rp[e], s);
#pragma unroll
      for (int e = 0; e < 8; ++e) s = fmaf(b2f(q1[e]), rp[32 + e], s);
      s += __shfl_xor(s, 16);
      s += __shfl_xor(s, 32);
      sp[p] = s;
    }
#pragma unroll
    for (int j = 0; j < 4; ++j)
      rqt[j] = (unsigned int)f2b(sp[2 * j]) |
               ((unsigned int)f2b(sp[2 * j + 1]) << 16);
  }

  int sw = (lc & 7);
  int a_b0 = lc * 64 + ((lr ^ sw) << 3);
  int a_b1 = lc * 64 + (((4 + lr) ^ sw) << 3);
  int pb0 = i_loc * 64 + ((lr ^ sw) << 3);
  int pb1 = i_loc * 64 + (((4 + lr) ^ sw) << 3);
  int swz8 = sw << 3;

  fx4 oacc[4] = {};
  float* attb = att + ((size_t)h * NT + i0) * NT;
  ushort_t* PS = Ps[jh];
  int jh64 = jh * 64;
  __syncthreads();  // tile0 staged

  int cur = 0;
  for (int tt = 0; tt < 24; ++tt) {
    if (tt < 23) {
      STAGE_K2(cur ^ 1, tt + 1);
      STAGE_V2(cur ^ 1, tt + 1);
    }
    const ushort_t* KS = Kd[cur][jh];
    const ushort_t* VS = Vd[cur][jh];
    const uchar_t* admp = admp0 + tt * 128;
    fx4 sacc[4] = {};
#pragma unroll
    for (int ja = 0; ja < 4; ++ja) {
      s8x a0 = *(const s8x*)(KS + a_b0 + ja * 1024);
      s8x a1 = *(const s8x*)(KS + a_b1 + ja * 1024);
      sacc[ja] = MFMA(a0, qf0, sacc[ja]);
      sacc[ja] = MFMA(a1, qf1, sacc[ja]);
    }
#pragma unroll
    for (int ja = 0; ja < 4; ++ja) {
      unsigned int aw = *(const unsigned int*)(admp + ja * 16);
      float p0 = EX2(sacc[ja][0] + rq_sel(rqt, aw & 7u) - lofs);
      float p1 = EX2(sacc[ja][1] + rq_sel(rqt, (aw >> 8) & 7u) - lofs);
      float p2 = EX2(sacc[ja][2] + rq_sel(rqt, (aw >> 16) & 7u) - lofs);
      float p3 = EX2(sacc[ja][3] + rq_sel(rqt, (aw >> 24) & 7u) - lofs);
      unsigned int w01 = (unsigned int)f2b(p0) | ((unsigned int)f2b(p1) << 16);
      unsigned int w23 = (unsigned int)f2b(p2) | ((unsigned int)f2b(p3) << 16);
      int cb = ja * 16 + lr * 4;
      *(unsigned int*)&PS[i_loc * 64 + (cb ^ swz8)] = w01;
      *(unsigned int*)&PS[i_loc * 64 + ((cb + 2) ^ swz8)] = w23;
    }
    // att copy-out: SAME-WAVE rows only (no barrier needed); drains under PV
    {
      int uu = ig * 64 + l;
      int row = uu >> 2, cs = (uu & 3) * 16;
      int rsw = (row & 7) << 3;
      uint4 A_ = *(const uint4*)&PS[row * 64 + (cs ^ rsw)];
      uint4 B_ = *(const uint4*)&PS[row * 64 + ((cs + 8) ^ rsw)];
      const ushort_t* ap = (const ushort_t*)&A_;
      const ushort_t* bp = (const ushort_t*)&B_;
      float* op = attb + (size_t)row * NT + tt * 128 + jh64 + cs;
      f4 o0 = {b2f(ap[0]), b2f(ap[1]), b2f(ap[2]), b2f(ap[3])};
      f4 o1 = {b2f(ap[4]), b2f(ap[5]), b2f(ap[6]), b2f(ap[7])};
      f4 o2 = {b2f(bp[0]), b2f(bp[1]), b2f(bp[2]), b2f(bp[3])};
      f4 o3 = {b2f(bp[4]), b2f(bp[5]), b2f(bp[6]), b2f(bp[7])};
      *(f4*)(op + 0) = o0;
      *(f4*)(op + 4) = o1;
      *(f4*)(op + 8) = o2;
      *(f4*)(op + 12) = o3;
    }
    // PV: Ot[d][i] += Vt[d][j] * P[i][j]
#pragma unroll
    for (int ks = 0; ks < 2; ++ks) {
      s8x pf = *(const s8x*)(PS + (ks == 0 ? pb0 : pb1));
#pragma unroll
      for (int nd = 0; nd < 4; ++nd) {
        s8x vf = *(const s8x*)(VS + (ks == 0 ? a_b0 : a_b1) + nd * 1024);
        oacc[nd] = MFMA(vf, pf, oacc[nd]);
      }
    }
    __syncthreads();
    cur ^= 1;
  }
#undef STAGE_K2
#undef STAGE_V2

  // merge O across j-halves via Ps (bf16), apply gate, write av
  ushort_t* PsF = &Ps[0][0];
  int swzO = (i_loc & 7) << 3;
  if (jh == 1) {
#pragma unroll
    for (int nd = 0; nd < 4; ++nd) {
      int d0 = nd * 16 + lr * 4;
      unsigned int lo = (unsigned int)f2b(oacc[nd][0]) |
                        ((unsigned int)f2b(oacc[nd][1]) << 16);
      unsigned int hi = (unsigned int)f2b(oacc[nd][2]) |
                        ((unsigned int)f2b(oacc[nd][3]) << 16);
      uint2 pk = {lo, hi};
      *(uint2*)&PsF[i_loc * 64 + (d0 ^ swzO)] = pk;
    }
  }
  __syncthreads();
  if (jh == 0) {
    const ushort_t* gp = xqkvg + (size_t)i * QS + 1536 + h * 64;
#pragma unroll
    for (int nd = 0; nd < 4; ++nd) {
      int d0 = nd * 16 + lr * 4;
      uint2 pk = *(const uint2*)&PsF[i_loc * 64 + (d0 ^ swzO)];
      const ushort_t* pp = (const ushort_t*)&pk;
      uint2 gk = *(const uint2*)(gp + d0);
      const ushort_t* gg = (const ushort_t*)&gk;
      ushort_t ot[4];
#pragma unroll
      for (int r = 0; r < 4; ++r)
        ot[r] = f2b((oacc[nd][r] + b2f(pp[r])) * b2f(gg[r]));
      *(uint2*)&av[(size_t)i * DIM + h * 64 + d0] = *(uint2*)ot;
    }
  }
}

extern "C" void kernel_launch(void* const* d_in, const int* in_sizes, int n_in,
                              void* d_out, int out_size, void* d_ws,
                              size_t ws_size, hipStream_t stream) {
  const float* x_in = (const float*)d_in[0];
  const int* adm = (const int*)d_in[1];
  const float* ln_att_s = (const float*)d_in[2];
  const float* ln_att_b = (const float*)d_in[3];
  const float* Wq = (const float*)d_in[4];
  const float* Wk = (const float*)d_in[5];
  const float* Wv = (const float*)d_in[6];
  const float* rel_k = (const float*)d_in[7];
  const float* Wg = (const float*)d_in[8];
  const float* bg = (const float*)d_in[9];
  const float* Wo = (const float*)d_in[10];
  const float* bo = (const float*)d_in[11];
  const float* ln_ff_s = (const float*)d_in[12];
  const float* ln_ff_b = (const float*)d_in[13];
  const float* W1 = (const float*)d_in[14];
  const float* b1 = (const float*)d_in[15];
  const float* W2 = (const float*)d_in[16];
  const float* b2 = (const float*)d_in[17];
  float* out = (float*)d_out;

  const size_t ND = (size_t)NT * DIM;
  char* ws = (char*)d_ws;
  float* x_cur = (float*)ws;                    // 6.29 MB
  float* y = (float*)(ws + 6291456);            // 6.29 MB
  ushort_t* xqkvg = (ushort_t*)(ws + 12582912); // 12.58 MB [3072][2048]
  ushort_t* avb = (ushort_t*)(ws + 25165824);   // 3.15 MB
  ushort_t* xnb = (ushort_t*)(ws + 28311552);   // 3.15 MB
  ushort_t* vbT = (ushort_t*)(ws + 31457280);   // 3.15 MB [8][64][3072]
  uchar_t* adm8 = (uchar_t*)(ws + 34603008);    // 9.44 MB
  float* lofsb = (float*)(ws + 44040192);       // 98 KB [8][3072]
  ushort_t* Wt = (ushort_t*)(ws + 44138496);    // 14.2 MB (3 layers)
  ushort_t* h1b = xqkvg;                        // FFN hidden aliases xqkvg

  adm8_kernel<<<(NT * NT) / 1024, 256, 0, stream>>>(adm, adm8);
  wprep_kernel<<<dim3(576, 3), 256, 0, stream>>>(Wq, Wk, Wv, Wg, Wo, W1, W2,
                                                 Wt);

  dim3 gQKVG(32, NT / 64);
  dim3 gA(8, NT / 64);
  dim3 gF1(16, NT / 64);
  dim3 gATT(NT / 32, NH);

  for (int n = 0; n < NL; ++n) {
    float* att = out + ND + (size_t)n * NH * NT * NT;
    const float* xprev = (n == 0) ? x_in : x_cur;   // residual stream input
    float* xout = (n == NL - 1) ? out : x_cur;      // final layer -> d_out
    ushort_t* Wtl = Wt + (size_t)n * 2359296;

    ln_bf16_kernel<<<NT, 256, 0, stream>>>(xprev, ln_att_s + n * DIM,
                                           ln_att_b + n * DIM, xnb);
    // fused QKVG: cols [0,512)=q(scaled), [512,1024)=k, [1024,1536)=v (also
    // emits vbT transpose), [1536,2048)=sigmoid(g+bg)
    gemm64<3, true><<<gQKVG, 256, 0, stream>>>(xnb, Wtl, bg + n * DIM, nullptr,
                                               xqkvg, DIM, QS, 1.0f, vbT);
    attn_ml_kernel<<<gATT, 256, 0, stream>>>(xqkvg, rel_k + n * PKN * DKH,
                                             adm8, lofsb);
    attn_pv_kernel<<<gATT, 256, 0, stream>>>(
        xqkvg, vbT, rel_k + n * PKN * DKH, adm8, lofsb, att, avb);
    // y = x + (av*gate)@Wo + bo   (gate already folded into avb)
    gemm64<0, false><<<gA, 256, 0, stream>>>(avb, Wtl + 1048576, bo + n * DIM,
                                             xprev, y, DIM, DIM, 1.0f, nullptr);
    ln_bf16_kernel<<<NT, 256, 0, stream>>>(y, ln_ff_s + n * DIM,
                                           ln_ff_b + n * DIM, xnb);
    gemm64<2, true><<<gF1, 256, 0, stream>>>(xnb, Wtl + 1310720, b1 + n * D2,
                                             nullptr, h1b, DIM, D2, 1.0f,
                                             nullptr);
    // x_new = x_old + ff  (last layer writes straight to d_out)
    gemm64<0, false><<<gA, 256, 0, stream>>>(h1b, Wtl + 1835008, b2 + n * DIM,
                                             xprev, xout, D2, DIM, 1.0f,
                                             nullptr);
  }
}